// Round 1
// baseline (4032.522 us; speedup 1.0000x reference)
//
#include <hip/hip_runtime.h>
#include <cstdint>

#define B_ 8
#define S_ 128
#define T_ 24
#define E_ 512
#define H_ 512
#define H3_ 1536
#define L_ 256
#define D_ 2048

__device__ __forceinline__ float fsig(float x) { return 1.0f / (1.0f + __expf(-x)); }
__device__ __forceinline__ float ftanh(float x) { return 1.0f - 2.0f / (1.0f + __expf(2.0f * x)); }
__device__ __forceinline__ float dot4(float4 a, float4 b) {
    return a.x * b.x + a.y * b.y + a.z * b.z + a.w * b.w;
}

// Coherent (LLC-level) scalar accesses: relaxed agent-scope atomics compile to
// global_load/store_dword sc0 sc1 — bypass non-coherent L1/L2, NO cache-wide
// maintenance ops (the round-1 killer was buffer_wbl2 from __threadfence).
__device__ __forceinline__ float cohLoad(const float* p) {
    return __hip_atomic_load((float*)p, __ATOMIC_RELAXED, __HIP_MEMORY_SCOPE_AGENT);
}
__device__ __forceinline__ void cohStore(float* p, float v) {
    __hip_atomic_store(p, v, __ATOMIC_RELAXED, __HIP_MEMORY_SCOPE_AGENT);
}
__device__ __forceinline__ void cohAdd(float* p, float v) {
    __hip_atomic_fetch_add(p, v, __ATOMIC_RELAXED, __HIP_MEMORY_SCOPE_AGENT);
}

// Cross-WG barrier: __syncthreads drains each wave's vmem (compiler emits
// s_waitcnt vmcnt(0) before s_barrier), so all write-through stores of the WG
// are at the LLC before tid0 signals. No-return atomic add pipelines at LLC.
__device__ __forceinline__ void sigBarrier(int* flag, int target) {
    __syncthreads();
    if (threadIdx.x == 0) {
        asm volatile("s_waitcnt vmcnt(0)" ::: "memory");
        __hip_atomic_fetch_add(flag, 1, __ATOMIC_RELAXED, __HIP_MEMORY_SCOPE_AGENT);
        while (__hip_atomic_load(flag, __ATOMIC_RELAXED, __HIP_MEMORY_SCOPE_AGENT) < target) {
            __builtin_amdgcn_s_sleep(1);
        }
        asm volatile("" ::: "memory");
    }
    __syncthreads();
}

// ---------------------------------------------------------------------------
__global__ void k_init(const int* __restrict__ pre, const int* __restrict__ post,
                       const int* __restrict__ trg,
                       int* __restrict__ idxPre, int* __restrict__ idxPost,
                       int* __restrict__ idxTok, int* __restrict__ cnt,
                       float* __restrict__ wEff) {
    int tid = blockIdx.x * 256 + threadIdx.x;  // grid 8 x 256 = 2048
    if (tid < 1024) {
        int s = tid >> 3, b = tid & 7;
        idxPre[tid]  = pre[b * S_ + s];
        idxPost[tid] = post[b * S_ + s];
    }
    if (tid < T_ * B_) {
        int t = tid >> 3, b = tid & 7;
        idxTok[tid] = (t == 0) ? pre[b * S_ + (S_ - 1)] : trg[b * T_ + (t - 1)];
    }
    if (tid < 32) cnt[tid] = 0;
    wEff[tid] = 0.f;
}

// ---------------------------------------------------------------------------
// Tiled f32 GEMM: C[m][n] = sum_k A[m][k]*B[n][k] + bias[n]
// ---------------------------------------------------------------------------
__global__ __launch_bounds__(256) void k_gemm(
    const float* __restrict__ A, const int* __restrict__ Aidx, int lda,
    const float* __restrict__ Bm, int ldb,
    const float* __restrict__ bias, float* __restrict__ C,
    int N, int K) {
    __shared__ float As[16][68];
    __shared__ float Bs[16][68];
    const int m0 = blockIdx.x * 64, n0 = blockIdx.y * 64;
    const int tid = threadIdx.x;
    const int tm = tid >> 2;
    const int tk = (tid & 3) << 2;
    const int tx = tid & 15, ty = tid >> 4;
    const int am = m0 + tm;
    const float* Arow = A + (size_t)(Aidx ? Aidx[am] : am) * lda;
    const float* Brow = Bm + (size_t)(n0 + tm) * ldb;
    float acc[4][4] = {};
    for (int k0 = 0; k0 < K; k0 += 16) {
        float4 av = *(const float4*)(Arow + k0 + tk);
        float4 bv = *(const float4*)(Brow + k0 + tk);
        __syncthreads();
        As[tk][tm] = av.x; As[tk + 1][tm] = av.y; As[tk + 2][tm] = av.z; As[tk + 3][tm] = av.w;
        Bs[tk][tm] = bv.x; Bs[tk + 1][tm] = bv.y; Bs[tk + 2][tm] = bv.z; Bs[tk + 3][tm] = bv.w;
        __syncthreads();
#pragma unroll
        for (int k = 0; k < 16; ++k) {
            float4 a4 = *(const float4*)(&As[k][ty << 2]);
            float4 b4 = *(const float4*)(&Bs[k][tx << 2]);
            float ar[4] = {a4.x, a4.y, a4.z, a4.w};
            float br[4] = {b4.x, b4.y, b4.z, b4.w};
#pragma unroll
            for (int i = 0; i < 4; ++i)
#pragma unroll
                for (int j = 0; j < 4; ++j) acc[i][j] += ar[i] * br[j];
        }
    }
    float4 bb = bias ? *(const float4*)(bias + n0 + (tx << 2)) : make_float4(0.f, 0.f, 0.f, 0.f);
#pragma unroll
    for (int i = 0; i < 4; ++i) {
        int m = m0 + (ty << 2) + i;
        float4 o;
        o.x = acc[i][0] + bb.x; o.y = acc[i][1] + bb.y;
        o.z = acc[i][2] + bb.z; o.w = acc[i][3] + bb.w;
        *(float4*)(C + (size_t)m * N + n0 + (tx << 2)) = o;
    }
}

// ---------------------------------------------------------------------------
// w_eff = fc_out_W @ fc_hid_W (2048-dot per col), split 128 WGs + f32 atomics.
// b_eff = fc_out_W . fc_hid_b + fc_out_b
// ---------------------------------------------------------------------------
__global__ void k_weff(const float* __restrict__ fcW, const float* __restrict__ fcB,
                       const float* __restrict__ voW, const float* __restrict__ voB,
                       float* __restrict__ wEff, float* __restrict__ bEff) {
    __shared__ float red[256];
    int bx = blockIdx.x;
    if (bx < 128) {
        int cblk = bx & 7, q = bx >> 3;
        int col = cblk * 256 + threadIdx.x;
        int j0 = q * 128;
        float acc = 0.f;
        for (int j = j0; j < j0 + 128; ++j) acc += voW[j] * fcW[(size_t)j * D_ + col];
        atomicAdd(wEff + col, acc);
    } else {
        float p = 0.f;
        for (int j = threadIdx.x; j < D_; j += 256) p += voW[j] * fcB[j];
        red[threadIdx.x] = p;
        __syncthreads();
        for (int s = 128; s > 0; s >>= 1) {
            if (threadIdx.x < s) red[threadIdx.x] += red[threadIdx.x + s];
            __syncthreads();
        }
        if (threadIdx.x == 0) bEff[0] = red[0] + voB[0];
    }
}

// ---------------------------------------------------------------------------
// Encoder scan, k-split chains: 16 independent chains (2 GRUs x 8 batches),
// 16 WGs per chain, WG p owns h-cols [32p, 32p+32). Weight slice (1536 rows x
// 32 cols = 96 floats/thread at 512 thr) is VGPR-resident, loaded once.
// Per step: 96 reg-FMA partial -> 6KB coalesced coherent store -> per-chain
// 16-WG barrier -> partial gather+reduce -> gates on own 32 cols (h-slice
// stays in LDS; NO h broadcast). Partial buffer double-buffered by t&1
// (barrier-at-distance-1 makes distance-2 reuse WAR-safe).
// ---------------------------------------------------------------------------
__global__ __launch_bounds__(512) void k_encoder(
    const float* __restrict__ giPre, const float* __restrict__ giPost,
    const float* __restrict__ WhhPre, const float* __restrict__ WhhPost,
    const float* __restrict__ bhhPre, const float* __restrict__ bhhPost,
    float* __restrict__ encOut, float* __restrict__ Pbuf, int* __restrict__ cnt) {
    const int bx = blockIdx.x;        // 0..255
    const int chain = bx >> 4;        // 0..15 : gr = chain>>3, b = chain&7
    const int p = bx & 15;            // k-slice owner
    const int gr = chain >> 3, b = chain & 7;
    const int kb = p << 5;            // first owned h-col
    const float* gi  = gr ? giPost : giPre;
    const float* Whh = gr ? WhhPost : WhhPre;
    const float* bhh = gr ? bhhPost : bhhPre;
    const size_t PHASE = (size_t)16 * 16 * 1536;          // per-t&1 buffer
    float* Pb0 = Pbuf + (size_t)chain * (16 * 1536);      // chain base (phase 0)
    int* flag = cnt + chain;
    const int tid = threadIdx.x;

    __shared__ float hS[32];             // own h-slice
    __shared__ float red[32 * 3 * 17];   // gather buffer [c][q][pp] padded
    __shared__ float ghS[96];            // reduced gh for own cols [q*32+c]

    // resident weights: rows {tid, 512+tid, 1024+tid} x cols [kb, kb+32)
    float w0[32], w1[32], w2[32];
    {
        const float* r0 = Whh + (size_t)tid * 512 + kb;
        const float* r1 = Whh + (size_t)(512 + tid) * 512 + kb;
        const float* r2 = Whh + (size_t)(1024 + tid) * 512 + kb;
#pragma unroll
        for (int kk = 0; kk < 32; ++kk) { w0[kk] = r0[kk]; w1[kk] = r1[kk]; w2[kk] = r2[kk]; }
    }
    float bh0 = 0.f, bh1 = 0.f, bh2 = 0.f;
    if (tid < 32) {
        bh0 = bhh[kb + tid];
        bh1 = bhh[512 + kb + tid];
        bh2 = bhh[1024 + kb + tid];
        hS[tid] = 0.f;
    }
    __syncthreads();

    for (int t = 0; t < S_; ++t) {
        // ---- partial gh over own k-slice: pure register FMA ----
        float4 hv[8];
#pragma unroll
        for (int i = 0; i < 8; ++i) hv[i] = *(const float4*)&hS[i * 4];
        float a0 = 0.f, a1 = 0.f, a2 = 0.f;
#pragma unroll
        for (int i = 0; i < 8; ++i) {
            const float hx = hv[i].x, hy = hv[i].y, hz = hv[i].z, hw = hv[i].w;
            a0 += w0[i * 4] * hx + w0[i * 4 + 1] * hy + w0[i * 4 + 2] * hz + w0[i * 4 + 3] * hw;
            a1 += w1[i * 4] * hx + w1[i * 4 + 1] * hy + w1[i * 4 + 2] * hz + w1[i * 4 + 3] * hw;
            a2 += w2[i * 4] * hx + w2[i * 4 + 1] * hy + w2[i * 4 + 2] * hz + w2[i * 4 + 3] * hw;
        }
        float* Pme = Pb0 + (t & 1) * PHASE + p * 1536;
        cohStore(Pme + tid, a0);
        cohStore(Pme + 512 + tid, a1);
        cohStore(Pme + 1024 + tid, a2);
        // prefetch gi for own cols (independent of h) before the wait
        float g0v = 0.f, g1v = 0.f, g2v = 0.f;
        if (tid < 32) {
            size_t gb = ((size_t)(t << 3) + b) * H3_;
            g0v = gi[gb + kb + tid];
            g1v = gi[gb + 512 + kb + tid];
            g2v = gi[gb + 1024 + kb + tid];
        }
        sigBarrier(flag, 16 * (t + 1));
        // ---- gather partials for own 32 cols from all 16 WGs ----
        {
            const float* Pch = Pb0 + (t & 1) * PHASE;
            int c = tid >> 4, pp = tid & 15;
            float s0 = cohLoad(Pch + pp * 1536 + kb + c);
            float s1 = cohLoad(Pch + pp * 1536 + 512 + kb + c);
            float s2 = cohLoad(Pch + pp * 1536 + 1024 + kb + c);
            red[(c * 3 + 0) * 17 + pp] = s0;
            red[(c * 3 + 1) * 17 + pp] = s1;
            red[(c * 3 + 2) * 17 + pp] = s2;
        }
        __syncthreads();
        if (tid < 96) {
            int c = tid & 31, q = tid >> 5;
            float s = 0.f;
#pragma unroll
            for (int pp = 0; pp < 16; ++pp) s += red[(c * 3 + q) * 17 + pp];
            ghS[q * 32 + c] = s;
        }
        __syncthreads();
        // ---- gates for own cols; h-slice stays local ----
        if (tid < 32) {
            float r = fsig(g0v + ghS[tid] + bh0);
            float z = fsig(g1v + ghS[32 + tid] + bh1);
            float n = ftanh(g2v + r * (ghS[64 + tid] + bh2));
            float h2 = (1.f - z) * n + z * hS[tid];
            hS[tid] = h2;
            encOut[(((size_t)(b << 8) + (gr << 7) + t) << 9) + kb + tid] = h2;
        }
        __syncthreads();
    }
}

// ---------------------------------------------------------------------------
__global__ void k_fcenc(const float* __restrict__ encOut, const float* __restrict__ W,
                        const float* __restrict__ bias, float* __restrict__ h) {
    int o = blockIdx.x * 256 + threadIdx.x;  // grid 16 -> 4096
    int b = o >> 9, j = o & 511;
    const float4* w4 = (const float4*)(W + (size_t)j * 1024);
    const float4* pre4 = (const float4*)(encOut + (((size_t)(b << 8) + 127) << 9));
    const float4* post4 = (const float4*)(encOut + (((size_t)(b << 8) + 255) << 9));
    float acc = bias[j];
    for (int k = 0; k < 128; ++k) acc += dot4(w4[k], pre4[k]);
    for (int k = 0; k < 128; ++k) acc += dot4(w4[128 + k], post4[k]);
    h[o] = ftanh(acc);
}

// enc_dot[b*256+l] = enc_out[b,l,:] . w_eff[0:512]
__global__ void k_encdot(const float* __restrict__ encOut, const float* __restrict__ wEff,
                         float* __restrict__ encDot) {
    int wid = threadIdx.x >> 6, lane = threadIdx.x & 63;
    int gw = blockIdx.x * 4 + wid;  // grid 32 -> 128 waves
    for (int o = gw; o < 2048; o += 128) {
        const float* row = encOut + ((size_t)o << 9);
        float s = 0.f;
        for (int k = lane; k < 512; k += 64) s += row[k] * wEff[k];
        for (int off = 32; off; off >>= 1) s += __shfl_down(s, off);
        if (lane == 0) encDot[o] = s;
    }
}

// eDot4[t*8+b] = emb[tok[t,b]] . w_eff[1536:2048]
__global__ void k_edot4(const float* __restrict__ emb, const int* __restrict__ idxTok,
                        const float* __restrict__ wEff, float* __restrict__ eDot4) {
    int o = blockIdx.x;  // grid 192, block 64
    int lane = threadIdx.x;
    const float* row = emb + (size_t)idxTok[o] * E_;
    const float* w = wEff + 1536;
    float s = 0.f;
    for (int k = lane; k < 512; k += 64) s += row[k] * w[k];
    for (int off = 32; off; off >>= 1) s += __shfl_down(s, off);
    if (lane == 0) eDot4[o] = s;
}

// ---------------------------------------------------------------------------
// Decoder scan: 128 WGs (b = bx>>4, s-slice = bx&15), 4 barriers/step.
// gh2 & weighted slices live in LDS; only hp/scores/h/gi2/c cross WGs.
// ---------------------------------------------------------------------------
__global__ __launch_bounds__(256) void k_decoder(
    const float* __restrict__ encOut, const float* __restrict__ encProj,
    const float* __restrict__ attnW, const float* __restrict__ attnV,
    const float* __restrict__ WihDec, const float* __restrict__ WhhDec,
    const float* __restrict__ bhhDec, const float* __restrict__ giE,
    const float* __restrict__ wEff, const float* __restrict__ bEff,
    const float* __restrict__ eDot4,
    float* __restrict__ h, float* __restrict__ hp, float* __restrict__ scores,
    float* __restrict__ gi2, float* __restrict__ c, int* __restrict__ cnt) {
    const int tid = threadIdx.x;
    const int bx = blockIdx.x;
    const int b = bx >> 4, s = bx & 15;
    int* flag = cnt + 16;
    int ep = 0;

    __shared__ float hB[512];
    __shared__ float hpS[512];
    __shared__ float gh2S[96];
    __shared__ float hpP[32][9];
    __shared__ float red[256];
    __shared__ float aS[256];
    __shared__ float wP[32][9];
    __shared__ float wS[32];

    for (int t = 0; t < T_; ++t) {
        // ---- A: stage h[b]; hp slice; gh2 slice (LDS); gi2 init; c init ----
        hB[tid] = cohLoad(h + (b << 9) + tid);
        hB[tid + 256] = cohLoad(h + (b << 9) + 256 + tid);
        __syncthreads();
        {
            int r = tid >> 3, p = tid & 7;
            const float4* w4 = (const float4*)(attnW + (size_t)(s * 32 + r) * 1024 + p * 64);
            const float4* h4 = (const float4*)(hB + p * 64);
            float acc = 0.f;
#pragma unroll
            for (int k = 0; k < 16; ++k) acc += dot4(w4[k], h4[k]);
            hpP[r][p] = acc;
        }
        if (tid < 96) {
            int g = tid >> 5, j = tid & 31;
            int n = g * 512 + s * 32 + j;
            const float4* w4 = (const float4*)(WhhDec + (size_t)n * 512);
            const float4* h4 = (const float4*)hB;
            float acc = bhhDec[n];
#pragma unroll 4
            for (int k = 0; k < 128; ++k) acc += dot4(w4[k], h4[k]);
            gh2S[tid] = acc;
            cohStore(gi2 + b * H3_ + n, giE[((size_t)(t << 3) + b) * H3_ + n]);
        }
        __syncthreads();
        if (tid < 32) {
            float a = 0.f;
#pragma unroll
            for (int p = 0; p < 8; ++p) a += hpP[tid][p];
            cohStore(hp + (b << 9) + s * 32 + tid, a);
        }
        if (s == 0 && tid == 0) cohStore(c + b * T_ + t, eDot4[t * 8 + b] + bEff[0]);
        sigBarrier(flag, 128 * (++ep));
        // ---- B: stage hp[b]; score rows l = s*16..s*16+16 ----
        hpS[tid] = cohLoad(hp + (b << 9) + tid);
        hpS[tid + 256] = cohLoad(hp + (b << 9) + 256 + tid);
        __syncthreads();
        {
            int wv = tid >> 6, lane = tid & 63;
#pragma unroll
            for (int i = 0; i < 4; ++i) {
                int l = s * 16 + wv * 4 + i;
                const float* eprow = encProj + (((size_t)(b << 8) + l) << 9);
                float sc = 0.f;
                for (int d = lane; d < 512; d += 64)
                    sc += attnV[d] * ftanh(eprow[d] + hpS[d]);
                for (int off = 32; off; off >>= 1) sc += __shfl_down(sc, off);
                if (lane == 0) cohStore(scores + (b << 8) + l, sc);
            }
        }
        sigBarrier(flag, 128 * (++ep));
        // ---- C: softmax; weighted slice; gi2 partial adds ----
        {
            float sc = cohLoad(scores + (b << 8) + tid);
            red[tid] = sc;
            __syncthreads();
            for (int st = 128; st > 0; st >>= 1) {
                if (tid < st) red[tid] = fmaxf(red[tid], red[tid + st]);
                __syncthreads();
            }
            float mx = red[0];
            __syncthreads();
            float ex = __expf(sc - mx);
            red[tid] = ex;
            __syncthreads();
            for (int st = 128; st > 0; st >>= 1) {
                if (tid < st) red[tid] += red[tid + st];
                __syncthreads();
            }
            float inv = 1.f / red[0];
            aS[tid] = ex * inv;
            __syncthreads();
        }
        {
            int j = tid & 31, p = tid >> 5;  // coalesced over j
            int hc = s * 32 + j;
            float acc = 0.f;
            for (int l = p * 32; l < p * 32 + 32; ++l)
                acc += aS[l] * encOut[(((size_t)(b << 8) + l) << 9) + hc];
            wP[j][p] = acc;
        }
        __syncthreads();
        if (tid < 32) {
            float a = 0.f;
#pragma unroll
            for (int p = 0; p < 8; ++p) a += wP[tid][p];
            wS[tid] = a;
        }
        __syncthreads();
        {
            int ks = s * 32;
#pragma unroll
            for (int i = 0; i < 6; ++i) {
                int n = i * 256 + tid;
                const float* w = WihDec + (size_t)n * 1024 + 512 + ks;
                float acc = 0.f;
#pragma unroll
                for (int k = 0; k < 32; ++k) acc += w[k] * wS[k];
                cohAdd(gi2 + b * H3_ + n, acc);
            }
        }
        sigBarrier(flag, 128 * (++ep));
        // ---- D: GRU update + logit-dot partials ----
        if (tid < 32) {
            int j = s * 32 + tid;
            float gr = cohLoad(gi2 + b * H3_ + j);
            float gz = cohLoad(gi2 + b * H3_ + 512 + j);
            float gn = cohLoad(gi2 + b * H3_ + 1024 + j);
            float r = fsig(gr + gh2S[tid]);
            float z = fsig(gz + gh2S[32 + tid]);
            float n = ftanh(gn + r * gh2S[64 + tid]);
            float h2 = (1.f - z) * n + z * hB[j];
            cohStore(h + (b << 9) + j, h2);
            float pc = h2 * wEff[1024 + j] + wS[tid] * wEff[512 + j];
#pragma unroll
            for (int off = 16; off; off >>= 1) pc += __shfl_down(pc, off);
            if (tid == 0) cohAdd(c + b * T_ + t, pc);
        }
        sigBarrier(flag, 128 * (++ep));
    }
}

// out[b,t,l-part] = enc_dot[b,l] + c[b,t]
__global__ void k_final(const float* __restrict__ encDot, const float* __restrict__ c,
                        float* __restrict__ out) {
    int idx = blockIdx.x * 256 + threadIdx.x;  // grid 192 -> 49152
    const int half = B_ * T_ * S_;
    int w = idx < half ? idx : idx - half;
    int b = w / (T_ * S_);
    int r = w % (T_ * S_);
    int t = r / S_, sidx = r % S_;
    int l = (idx < half) ? sidx : (S_ + sidx);
    out[idx] = encDot[b * L_ + l] + c[b * T_ + t];
}

// ---------------------------------------------------------------------------
extern "C" void kernel_launch(void* const* d_in, const int* in_sizes, int n_in,
                              void* d_out, int out_size, void* d_ws, size_t ws_size,
                              hipStream_t stream) {
    const int* pre = (const int*)d_in[0];
    const int* post = (const int*)d_in[1];
    const int* trg = (const int*)d_in[2];
    const float* emb = (const float*)d_in[3];
    const float* WihPre = (const float*)d_in[4];
    const float* WhhPre = (const float*)d_in[5];
    const float* bihPre = (const float*)d_in[6];
    const float* bhhPre = (const float*)d_in[7];
    const float* WihPost = (const float*)d_in[8];
    const float* WhhPost = (const float*)d_in[9];
    const float* bihPost = (const float*)d_in[10];
    const float* bhhPost = (const float*)d_in[11];
    const float* fcEncW = (const float*)d_in[12];
    const float* fcEncB = (const float*)d_in[13];
    const float* attnW = (const float*)d_in[14];
    const float* attnB = (const float*)d_in[15];
    const float* attnV = (const float*)d_in[16];
    const float* WihDec = (const float*)d_in[17];
    const float* WhhDec = (const float*)d_in[18];
    const float* bihDec = (const float*)d_in[19];
    const float* bhhDec = (const float*)d_in[20];
    const float* fcHidW = (const float*)d_in[21];
    const float* fcHidB = (const float*)d_in[22];
    const float* fcOutW = (const float*)d_in[23];
    const float* fcOutB = (const float*)d_in[24];
    float* outp = (float*)d_out;

    float* base = (float*)d_ws;
    size_t off = 0;
    auto alloc = [&](size_t n) {
        float* p = base + off;
        off += (n + 63) & ~(size_t)63;
        return p;
    };
    float* giPre = alloc(1024 * 1536);
    float* giPost = alloc(1024 * 1536);
    float* giE = alloc(192 * 1536);
    float* encOut = alloc(8 * 256 * 512);
    float* encProj = alloc(8 * 256 * 512);
    float* wEff = alloc(2048);
    float* bEff = alloc(64);
    float* encDot = alloc(2048);
    float* eDot4 = alloc(256);
    float* hBuf = alloc(4096);
    float* hpBuf = alloc(4096);
    float* scoresBuf = alloc(2048);
    float* gi2 = alloc(12288);
    float* cBuf = alloc(256);
    float* Pbuf = alloc(2 * 16 * 16 * 1536);
    int* idxPre = (int*)alloc(1024);
    int* idxPost = (int*)alloc(1024);
    int* idxTok = (int*)alloc(256);
    int* cnt = (int*)alloc(64);

    k_init<<<8, 256, 0, stream>>>(pre, post, trg, idxPre, idxPost, idxTok, cnt, wEff);
    k_weff<<<129, 256, 0, stream>>>(fcHidW, fcHidB, fcOutW, fcOutB, wEff, bEff);
    k_gemm<<<dim3(16, 24), 256, 0, stream>>>(emb, idxPre, 512, WihPre, 512, bihPre, giPre, 1536, 512);
    k_gemm<<<dim3(16, 24), 256, 0, stream>>>(emb, idxPost, 512, WihPost, 512, bihPost, giPost, 1536, 512);
    k_gemm<<<dim3(3, 24), 256, 0, stream>>>(emb, idxTok, 512, WihDec, 1024, bihDec, giE, 1536, 512);
    k_encoder<<<256, 512, 0, stream>>>(giPre, giPost, WhhPre, WhhPost, bhhPre, bhhPost,
                                       encOut, Pbuf, cnt);
    k_gemm<<<dim3(32, 8), 256, 0, stream>>>(encOut, nullptr, 512, attnW + 512, 1024, attnB, encProj, 512, 512);
    k_fcenc<<<16, 256, 0, stream>>>(encOut, fcEncW, fcEncB, hBuf);
    k_encdot<<<32, 256, 0, stream>>>(encOut, wEff, encDot);
    k_edot4<<<192, 64, 0, stream>>>(emb, idxTok, wEff, eDot4);
    k_decoder<<<128, 256, 0, stream>>>(encOut, encProj, attnW, attnV, WihDec, WhhDec, bhhDec,
                                       giE, wEff, bEff, eDot4, hBuf, hpBuf, scoresBuf,
                                       gi2, cBuf, cnt);
    k_final<<<192, 256, 0, stream>>>(encDot, cBuf, outp);
}

// Round 2
// 1619.831 us; speedup vs baseline: 2.4895x; 2.4895x over previous
//
#include <hip/hip_runtime.h>
#include <cstdint>

#define B_ 8
#define S_ 128
#define T_ 24
#define E_ 512
#define H_ 512
#define H3_ 1536
#define L_ 256
#define D_ 2048

typedef unsigned long long u64;

__device__ __forceinline__ float fsig(float x) { return 1.0f / (1.0f + __expf(-x)); }
__device__ __forceinline__ float ftanh(float x) { return 1.0f - 2.0f / (1.0f + __expf(2.0f * x)); }
__device__ __forceinline__ float dot4(float4 a, float4 b) {
    return a.x * b.x + a.y * b.y + a.z * b.z + a.w * b.w;
}

// Coherent (LLC-level) scalar accesses: relaxed agent-scope atomics compile to
// global_load/store sc0 sc1 — bypass non-coherent L1/L2, no cache-wide flushes.
__device__ __forceinline__ float cohLoad(const float* p) {
    return __hip_atomic_load((float*)p, __ATOMIC_RELAXED, __HIP_MEMORY_SCOPE_AGENT);
}
__device__ __forceinline__ void cohStore(float* p, float v) {
    __hip_atomic_store(p, v, __ATOMIC_RELAXED, __HIP_MEMORY_SCOPE_AGENT);
}
__device__ __forceinline__ void cohAdd(float* p, float v) {
    __hip_atomic_fetch_add(p, v, __ATOMIC_RELAXED, __HIP_MEMORY_SCOPE_AGENT);
}
__device__ __forceinline__ u64 cohLoadU64(const u64* p) {
    return __hip_atomic_load((u64*)p, __ATOMIC_RELAXED, __HIP_MEMORY_SCOPE_AGENT);
}
__device__ __forceinline__ void cohStoreU64(u64* p, u64 v) {
    __hip_atomic_store(p, v, __ATOMIC_RELAXED, __HIP_MEMORY_SCOPE_AGENT);
}
__device__ __forceinline__ float2 asF2(u64 v) { union { u64 u; float2 f; } x; x.u = v; return x.f; }
__device__ __forceinline__ u64 packF2(float v, float tag) { union { float2 f; u64 u; } x; x.f = make_float2(v, tag); return x.u; }

// Counter barrier (decoder only, now per-batch groups of 16 WGs).
__device__ __forceinline__ void sigBarrier(int* flag, int target) {
    __syncthreads();
    if (threadIdx.x == 0) {
        asm volatile("s_waitcnt vmcnt(0)" ::: "memory");
        __hip_atomic_fetch_add(flag, 1, __ATOMIC_RELAXED, __HIP_MEMORY_SCOPE_AGENT);
        while (__hip_atomic_load(flag, __ATOMIC_RELAXED, __HIP_MEMORY_SCOPE_AGENT) < target) {
            __builtin_amdgcn_s_sleep(1);
        }
        asm volatile("" ::: "memory");
    }
    __syncthreads();
}

// ---------------------------------------------------------------------------
__global__ void k_init(const int* __restrict__ pre, const int* __restrict__ post,
                       const int* __restrict__ trg,
                       int* __restrict__ idxPre, int* __restrict__ idxPost,
                       int* __restrict__ idxTok, int* __restrict__ cnt,
                       float* __restrict__ wEff) {
    int tid = blockIdx.x * 256 + threadIdx.x;  // grid 8 x 256 = 2048
    if (tid < 1024) {
        int s = tid >> 3, b = tid & 7;
        idxPre[tid]  = pre[b * S_ + s];
        idxPost[tid] = post[b * S_ + s];
    }
    if (tid < T_ * B_) {
        int t = tid >> 3, b = tid & 7;
        idxTok[tid] = (t == 0) ? pre[b * S_ + (S_ - 1)] : trg[b * T_ + (t - 1)];
    }
    if (tid < 512) cnt[tid] = 0;
    wEff[tid] = 0.f;
}

// Zero the tagged partial-exchange buffer (tags must start != any step tag).
__global__ void k_clear(u64* __restrict__ p, int n) {
    int i = blockIdx.x * 256 + threadIdx.x;
    int stride = gridDim.x * 256;
    for (; i < n; i += stride) p[i] = 0ull;
}

// ---------------------------------------------------------------------------
// Tiled f32 GEMM: C[m][n] = sum_k A[m][k]*B[n][k] + bias[n]
// ---------------------------------------------------------------------------
__global__ __launch_bounds__(256) void k_gemm(
    const float* __restrict__ A, const int* __restrict__ Aidx, int lda,
    const float* __restrict__ Bm, int ldb,
    const float* __restrict__ bias, float* __restrict__ C,
    int N, int K) {
    __shared__ float As[16][68];
    __shared__ float Bs[16][68];
    const int m0 = blockIdx.x * 64, n0 = blockIdx.y * 64;
    const int tid = threadIdx.x;
    const int tm = tid >> 2;
    const int tk = (tid & 3) << 2;
    const int tx = tid & 15, ty = tid >> 4;
    const int am = m0 + tm;
    const float* Arow = A + (size_t)(Aidx ? Aidx[am] : am) * lda;
    const float* Brow = Bm + (size_t)(n0 + tm) * ldb;
    float acc[4][4] = {};
    for (int k0 = 0; k0 < K; k0 += 16) {
        float4 av = *(const float4*)(Arow + k0 + tk);
        float4 bv = *(const float4*)(Brow + k0 + tk);
        __syncthreads();
        As[tk][tm] = av.x; As[tk + 1][tm] = av.y; As[tk + 2][tm] = av.z; As[tk + 3][tm] = av.w;
        Bs[tk][tm] = bv.x; Bs[tk + 1][tm] = bv.y; Bs[tk + 2][tm] = bv.z; Bs[tk + 3][tm] = bv.w;
        __syncthreads();
#pragma unroll
        for (int k = 0; k < 16; ++k) {
            float4 a4 = *(const float4*)(&As[k][ty << 2]);
            float4 b4 = *(const float4*)(&Bs[k][tx << 2]);
            float ar[4] = {a4.x, a4.y, a4.z, a4.w};
            float br[4] = {b4.x, b4.y, b4.z, b4.w};
#pragma unroll
            for (int i = 0; i < 4; ++i)
#pragma unroll
                for (int j = 0; j < 4; ++j) acc[i][j] += ar[i] * br[j];
        }
    }
    float4 bb = bias ? *(const float4*)(bias + n0 + (tx << 2)) : make_float4(0.f, 0.f, 0.f, 0.f);
#pragma unroll
    for (int i = 0; i < 4; ++i) {
        int m = m0 + (ty << 2) + i;
        float4 o;
        o.x = acc[i][0] + bb.x; o.y = acc[i][1] + bb.y;
        o.z = acc[i][2] + bb.z; o.w = acc[i][3] + bb.w;
        *(float4*)(C + (size_t)m * N + n0 + (tx << 2)) = o;
    }
}

// ---------------------------------------------------------------------------
// w_eff = fc_out_W @ fc_hid_W (2048-dot per col), split 128 WGs + f32 atomics.
// b_eff = fc_out_W . fc_hid_b + fc_out_b
// ---------------------------------------------------------------------------
__global__ void k_weff(const float* __restrict__ fcW, const float* __restrict__ fcB,
                       const float* __restrict__ voW, const float* __restrict__ voB,
                       float* __restrict__ wEff, float* __restrict__ bEff) {
    __shared__ float red[256];
    int bx = blockIdx.x;
    if (bx < 128) {
        int cblk = bx & 7, q = bx >> 3;
        int col = cblk * 256 + threadIdx.x;
        int j0 = q * 128;
        float acc = 0.f;
        for (int j = j0; j < j0 + 128; ++j) acc += voW[j] * fcW[(size_t)j * D_ + col];
        atomicAdd(wEff + col, acc);
    } else {
        float p = 0.f;
        for (int j = threadIdx.x; j < D_; j += 256) p += voW[j] * fcB[j];
        red[threadIdx.x] = p;
        __syncthreads();
        for (int s = 128; s > 0; s >>= 1) {
            if (threadIdx.x < s) red[threadIdx.x] += red[threadIdx.x + s];
            __syncthreads();
        }
        if (threadIdx.x == 0) bEff[0] = red[0] + voB[0];
    }
}

// ---------------------------------------------------------------------------
// Encoder scan, k-split chains with TAGGED-DATA sync (no barriers, no flags).
// 16 chains x 16 WGs; WG p owns h-cols [32p,32p+32). launch_bounds(512,2)
// gives a 256-VGPR budget so the 96-float weight slice is truly
// register-resident (round-1's 68-VGPR build spilled it to scratch).
// Per step: 96 reg-FMA -> write partials as {val,tag=t+1} 8B atoms into
// reader-major layout [q][gate][p][c] (coalesced both sides) -> poll own
// block's 48 slots/thread-triple until tags match -> LDS reduce -> gates.
// One LLC round trip per step, zero RMW atomics. Double-buffered by t&1;
// dataflow (tag t+2 requires consuming t+1) makes 2 buffers WAR-safe.
// ---------------------------------------------------------------------------
__global__ __launch_bounds__(512, 2) void k_encoder(
    const float* __restrict__ giPre, const float* __restrict__ giPost,
    const float* __restrict__ WhhPre, const float* __restrict__ WhhPost,
    const float* __restrict__ bhhPre, const float* __restrict__ bhhPost,
    float* __restrict__ encOut, float* __restrict__ Pbuf) {
    const int bx = blockIdx.x;        // 0..255
    const int chain = bx >> 4;        // gr = chain>>3, b = chain&7
    const int p = bx & 15;            // owned h-col block
    const int gr = chain >> 3, b = chain & 7;
    const int kb = p << 5;
    const float* gi  = gr ? giPost : giPre;
    const float* Whh = gr ? WhhPost : WhhPre;
    const float* bhh = gr ? bhhPost : bhhPre;
    const int PH = 24576;                              // slots per phase per chain
    u64* PbU = (u64*)Pbuf + (size_t)chain * (2 * PH);
    const int tid = threadIdx.x;

    __shared__ float hS[32];
    __shared__ float red[96 * 17];
    __shared__ float ghS[96];

    // register-resident weights: rows {tid, 512+tid, 1024+tid}, cols [kb,kb+32)
    float w0[32], w1[32], w2[32];
    {
        const float* r0 = Whh + (size_t)tid * 512 + kb;
        const float* r1 = r0 + (size_t)512 * 512;
        const float* r2 = r1 + (size_t)512 * 512;
#pragma unroll
        for (int kk = 0; kk < 32; ++kk) { w0[kk] = r0[kk]; w1[kk] = r1[kk]; w2[kk] = r2[kk]; }
    }
    float bh0 = 0.f, bh1 = 0.f, bh2 = 0.f;
    if (tid < 32) {
        bh0 = bhh[kb + tid];
        bh1 = bhh[512 + kb + tid];
        bh2 = bhh[1024 + kb + tid];
        hS[tid] = 0.f;
    }
    // writer: col c=tid of each gate -> reader q=tid>>5, slot [q][g][p][tid&31]
    const int wslot = (tid >> 5) * 1536 + p * 32 + (tid & 31);
    // reader: own block p, slot [p][g][pp=tid>>5][c=tid&31]
    const int rslot = p * 1536 + (tid >> 5) * 32 + (tid & 31);
    __syncthreads();

    for (int t = 0; t < S_; ++t) {
        float4 hv[8];
#pragma unroll
        for (int i = 0; i < 8; ++i) hv[i] = *(const float4*)&hS[i * 4];
        float a0 = 0.f, a1 = 0.f, a2 = 0.f;
#pragma unroll
        for (int i = 0; i < 8; ++i) {
            const float hx = hv[i].x, hy = hv[i].y, hz = hv[i].z, hw = hv[i].w;
            a0 += w0[4 * i] * hx + w0[4 * i + 1] * hy + w0[4 * i + 2] * hz + w0[4 * i + 3] * hw;
            a1 += w1[4 * i] * hx + w1[4 * i + 1] * hy + w1[4 * i + 2] * hz + w1[4 * i + 3] * hw;
            a2 += w2[4 * i] * hx + w2[4 * i + 1] * hy + w2[4 * i + 2] * hz + w2[4 * i + 3] * hw;
        }
        const float tagf = (float)(t + 1);
        u64* Pw = PbU + (t & 1) * PH;
        cohStoreU64(Pw + wslot,        packF2(a0, tagf));
        cohStoreU64(Pw + wslot + 512,  packF2(a1, tagf));
        cohStoreU64(Pw + wslot + 1024, packF2(a2, tagf));
        // prefetch gi (independent of exchange)
        float g0v = 0.f, g1v = 0.f, g2v = 0.f;
        if (tid < 32) {
            size_t gb = ((size_t)(t << 3) + b) * H3_;
            g0v = gi[gb + kb + tid];
            g1v = gi[gb + 512 + kb + tid];
            g2v = gi[gb + 1024 + kb + tid];
        }
        asm volatile("" ::: "memory");  // keep stores issued before poll loop
        const u64* Pr = PbU + (t & 1) * PH;
        float s0 = 0.f, s1 = 0.f, s2 = 0.f;
        bool o0 = false, o1 = false, o2 = false;
        do {
            if (!o0) { float2 f = asF2(cohLoadU64(Pr + rslot));        if (f.y == tagf) { s0 = f.x; o0 = true; } }
            if (!o1) { float2 f = asF2(cohLoadU64(Pr + rslot + 512));  if (f.y == tagf) { s1 = f.x; o1 = true; } }
            if (!o2) { float2 f = asF2(cohLoadU64(Pr + rslot + 1024)); if (f.y == tagf) { s2 = f.x; o2 = true; } }
        } while (!(o0 && o1 && o2));
        {
            int rp = tid >> 5, rc = tid & 31;
            red[(0 * 32 + rc) * 17 + rp] = s0;
            red[(1 * 32 + rc) * 17 + rp] = s1;
            red[(2 * 32 + rc) * 17 + rp] = s2;
        }
        __syncthreads();
        if (tid < 96) {
            int g = tid >> 5, c = tid & 31;
            float s = 0.f;
#pragma unroll
            for (int pp = 0; pp < 16; ++pp) s += red[(g * 32 + c) * 17 + pp];
            ghS[g * 32 + c] = s;
        }
        __syncthreads();
        if (tid < 32) {
            float r = fsig(g0v + ghS[tid] + bh0);
            float z = fsig(g1v + ghS[32 + tid] + bh1);
            float n = ftanh(g2v + r * (ghS[64 + tid] + bh2));
            float h2 = (1.f - z) * n + z * hS[tid];
            hS[tid] = h2;
            encOut[(((size_t)(b << 8) + (gr << 7) + t) << 9) + kb + tid] = h2;
        }
        __syncthreads();
    }
}

// ---------------------------------------------------------------------------
__global__ void k_fcenc(const float* __restrict__ encOut, const float* __restrict__ W,
                        const float* __restrict__ bias, float* __restrict__ h) {
    int o = blockIdx.x * 256 + threadIdx.x;  // grid 16 -> 4096
    int b = o >> 9, j = o & 511;
    const float4* w4 = (const float4*)(W + (size_t)j * 1024);
    const float4* pre4 = (const float4*)(encOut + (((size_t)(b << 8) + 127) << 9));
    const float4* post4 = (const float4*)(encOut + (((size_t)(b << 8) + 255) << 9));
    float acc = bias[j];
    for (int k = 0; k < 128; ++k) acc += dot4(w4[k], pre4[k]);
    for (int k = 0; k < 128; ++k) acc += dot4(w4[128 + k], post4[k]);
    h[o] = ftanh(acc);
}

// enc_dot[b*256+l] = enc_out[b,l,:] . w_eff[0:512]
__global__ void k_encdot(const float* __restrict__ encOut, const float* __restrict__ wEff,
                         float* __restrict__ encDot) {
    int wid = threadIdx.x >> 6, lane = threadIdx.x & 63;
    int gw = blockIdx.x * 4 + wid;  // grid 32 -> 128 waves
    for (int o = gw; o < 2048; o += 128) {
        const float* row = encOut + ((size_t)o << 9);
        float s = 0.f;
        for (int k = lane; k < 512; k += 64) s += row[k] * wEff[k];
        for (int off = 32; off; off >>= 1) s += __shfl_down(s, off);
        if (lane == 0) encDot[o] = s;
    }
}

// eDot4[t*8+b] = emb[tok[t,b]] . w_eff[1536:2048]
__global__ void k_edot4(const float* __restrict__ emb, const int* __restrict__ idxTok,
                        const float* __restrict__ wEff, float* __restrict__ eDot4) {
    int o = blockIdx.x;  // grid 192, block 64
    int lane = threadIdx.x;
    const float* row = emb + (size_t)idxTok[o] * E_;
    const float* w = wEff + 1536;
    float s = 0.f;
    for (int k = lane; k < 512; k += 64) s += row[k] * w[k];
    for (int off = 32; off; off >>= 1) s += __shfl_down(s, off);
    if (lane == 0) eDot4[o] = s;
}

// ---------------------------------------------------------------------------
// Decoder scan: 128 WGs (b = bx>>4, s-slice = bx&15), 4 barriers/step.
// All cross-WG data (hp, scores, gi2, h, c) is per-batch, so barriers are now
// PER-BATCH groups of 16 WGs on separate cache lines (round-1: all 128 WGs
// RMW-hammered one line -> ~10us/phase of LLC serialization).
// ---------------------------------------------------------------------------
__global__ __launch_bounds__(256) void k_decoder(
    const float* __restrict__ encOut, const float* __restrict__ encProj,
    const float* __restrict__ attnW, const float* __restrict__ attnV,
    const float* __restrict__ WihDec, const float* __restrict__ WhhDec,
    const float* __restrict__ bhhDec, const float* __restrict__ giE,
    const float* __restrict__ wEff, const float* __restrict__ bEff,
    const float* __restrict__ eDot4,
    float* __restrict__ h, float* __restrict__ hp, float* __restrict__ scores,
    float* __restrict__ gi2, float* __restrict__ c, int* __restrict__ cnt) {
    const int tid = threadIdx.x;
    const int bx = blockIdx.x;
    const int b = bx >> 4, s = bx & 15;
    int* flag = cnt + 64 + (b << 5);  // per-batch flag, 128B apart
    int ep = 0;

    __shared__ float hB[512];
    __shared__ float hpS[512];
    __shared__ float gh2S[96];
    __shared__ float hpP[32][9];
    __shared__ float red[256];
    __shared__ float aS[256];
    __shared__ float wP[32][9];
    __shared__ float wS[32];

    for (int t = 0; t < T_; ++t) {
        // ---- A: stage h[b]; hp slice; gh2 slice (LDS); gi2 init; c init ----
        hB[tid] = cohLoad(h + (b << 9) + tid);
        hB[tid + 256] = cohLoad(h + (b << 9) + 256 + tid);
        __syncthreads();
        {
            int r = tid >> 3, p = tid & 7;
            const float4* w4 = (const float4*)(attnW + (size_t)(s * 32 + r) * 1024 + p * 64);
            const float4* h4 = (const float4*)(hB + p * 64);
            float acc = 0.f;
#pragma unroll
            for (int k = 0; k < 16; ++k) acc += dot4(w4[k], h4[k]);
            hpP[r][p] = acc;
        }
        if (tid < 96) {
            int g = tid >> 5, j = tid & 31;
            int n = g * 512 + s * 32 + j;
            const float4* w4 = (const float4*)(WhhDec + (size_t)n * 512);
            const float4* h4 = (const float4*)hB;
            float acc = bhhDec[n];
#pragma unroll 4
            for (int k = 0; k < 128; ++k) acc += dot4(w4[k], h4[k]);
            gh2S[tid] = acc;
            cohStore(gi2 + b * H3_ + n, giE[((size_t)(t << 3) + b) * H3_ + n]);
        }
        __syncthreads();
        if (tid < 32) {
            float a = 0.f;
#pragma unroll
            for (int p = 0; p < 8; ++p) a += hpP[tid][p];
            cohStore(hp + (b << 9) + s * 32 + tid, a);
        }
        if (s == 0 && tid == 0) cohStore(c + b * T_ + t, eDot4[t * 8 + b] + bEff[0]);
        sigBarrier(flag, 16 * (++ep));
        // ---- B: stage hp[b]; score rows l = s*16..s*16+16 ----
        hpS[tid] = cohLoad(hp + (b << 9) + tid);
        hpS[tid + 256] = cohLoad(hp + (b << 9) + 256 + tid);
        __syncthreads();
        {
            int wv = tid >> 6, lane = tid & 63;
#pragma unroll
            for (int i = 0; i < 4; ++i) {
                int l = s * 16 + wv * 4 + i;
                const float* eprow = encProj + (((size_t)(b << 8) + l) << 9);
                float sc = 0.f;
                for (int d = lane; d < 512; d += 64)
                    sc += attnV[d] * ftanh(eprow[d] + hpS[d]);
                for (int off = 32; off; off >>= 1) sc += __shfl_down(sc, off);
                if (lane == 0) cohStore(scores + (b << 8) + l, sc);
            }
        }
        sigBarrier(flag, 16 * (++ep));
        // ---- C: softmax; weighted slice; gi2 partial adds ----
        {
            float sc = cohLoad(scores + (b << 8) + tid);
            red[tid] = sc;
            __syncthreads();
            for (int st = 128; st > 0; st >>= 1) {
                if (tid < st) red[tid] = fmaxf(red[tid], red[tid + st]);
                __syncthreads();
            }
            float mx = red[0];
            __syncthreads();
            float ex = __expf(sc - mx);
            red[tid] = ex;
            __syncthreads();
            for (int st = 128; st > 0; st >>= 1) {
                if (tid < st) red[tid] += red[tid + st];
                __syncthreads();
            }
            float inv = 1.f / red[0];
            aS[tid] = ex * inv;
            __syncthreads();
        }
        {
            int j = tid & 31, p = tid >> 5;  // coalesced over j
            int hc = s * 32 + j;
            float acc = 0.f;
            for (int l = p * 32; l < p * 32 + 32; ++l)
                acc += aS[l] * encOut[(((size_t)(b << 8) + l) << 9) + hc];
            wP[j][p] = acc;
        }
        __syncthreads();
        if (tid < 32) {
            float a = 0.f;
#pragma unroll
            for (int p = 0; p < 8; ++p) a += wP[tid][p];
            wS[tid] = a;
        }
        __syncthreads();
        {
            int ks = s * 32;
#pragma unroll
            for (int i = 0; i < 6; ++i) {
                int n = i * 256 + tid;
                const float* w = WihDec + (size_t)n * 1024 + 512 + ks;
                float acc = 0.f;
#pragma unroll
                for (int k = 0; k < 32; ++k) acc += w[k] * wS[k];
                cohAdd(gi2 + b * H3_ + n, acc);
            }
        }
        sigBarrier(flag, 16 * (++ep));
        // ---- D: GRU update + logit-dot partials ----
        if (tid < 32) {
            int j = s * 32 + tid;
            float gr = cohLoad(gi2 + b * H3_ + j);
            float gz = cohLoad(gi2 + b * H3_ + 512 + j);
            float gn = cohLoad(gi2 + b * H3_ + 1024 + j);
            float r = fsig(gr + gh2S[tid]);
            float z = fsig(gz + gh2S[32 + tid]);
            float n = ftanh(gn + r * gh2S[64 + tid]);
            float h2 = (1.f - z) * n + z * hB[j];
            cohStore(h + (b << 9) + j, h2);
            float pc = h2 * wEff[1024 + j] + wS[tid] * wEff[512 + j];
#pragma unroll
            for (int off = 16; off; off >>= 1) pc += __shfl_down(pc, off);
            if (tid == 0) cohAdd(c + b * T_ + t, pc);
        }
        sigBarrier(flag, 16 * (++ep));
    }
}

// out[b,t,l-part] = enc_dot[b,l] + c[b,t]
__global__ void k_final(const float* __restrict__ encDot, const float* __restrict__ c,
                        float* __restrict__ out) {
    int idx = blockIdx.x * 256 + threadIdx.x;  // grid 192 -> 49152
    const int half = B_ * T_ * S_;
    int w = idx < half ? idx : idx - half;
    int b = w / (T_ * S_);
    int r = w % (T_ * S_);
    int t = r / S_, sidx = r % S_;
    int l = (idx < half) ? sidx : (S_ + sidx);
    out[idx] = encDot[b * L_ + l] + c[b * T_ + t];
}

// ---------------------------------------------------------------------------
extern "C" void kernel_launch(void* const* d_in, const int* in_sizes, int n_in,
                              void* d_out, int out_size, void* d_ws, size_t ws_size,
                              hipStream_t stream) {
    const int* pre = (const int*)d_in[0];
    const int* post = (const int*)d_in[1];
    const int* trg = (const int*)d_in[2];
    const float* emb = (const float*)d_in[3];
    const float* WihPre = (const float*)d_in[4];
    const float* WhhPre = (const float*)d_in[5];
    const float* bihPre = (const float*)d_in[6];
    const float* bhhPre = (const float*)d_in[7];
    const float* WihPost = (const float*)d_in[8];
    const float* WhhPost = (const float*)d_in[9];
    const float* bihPost = (const float*)d_in[10];
    const float* bhhPost = (const float*)d_in[11];
    const float* fcEncW = (const float*)d_in[12];
    const float* fcEncB = (const float*)d_in[13];
    const float* attnW = (const float*)d_in[14];
    const float* attnB = (const float*)d_in[15];
    const float* attnV = (const float*)d_in[16];
    const float* WihDec = (const float*)d_in[17];
    const float* WhhDec = (const float*)d_in[18];
    const float* bihDec = (const float*)d_in[19];
    const float* bhhDec = (const float*)d_in[20];
    const float* fcHidW = (const float*)d_in[21];
    const float* fcHidB = (const float*)d_in[22];
    const float* fcOutW = (const float*)d_in[23];
    const float* fcOutB = (const float*)d_in[24];
    float* outp = (float*)d_out;

    float* base = (float*)d_ws;
    size_t off = 0;
    auto alloc = [&](size_t n) {
        float* p = base + off;
        off += (n + 63) & ~(size_t)63;
        return p;
    };
    float* giPre = alloc(1024 * 1536);
    float* giPost = alloc(1024 * 1536);
    float* giE = alloc(192 * 1536);
    float* encOut = alloc(8 * 256 * 512);
    float* encProj = alloc(8 * 256 * 512);
    float* wEff = alloc(2048);
    float* bEff = alloc(64);
    float* encDot = alloc(2048);
    float* eDot4 = alloc(256);
    float* hBuf = alloc(4096);
    float* hpBuf = alloc(4096);
    float* scoresBuf = alloc(2048);
    float* gi2 = alloc(12288);
    float* cBuf = alloc(256);
    float* Pbuf = alloc(2 * 16 * 24576 * 2);  // u64 slots {val,tag}
    int* idxPre = (int*)alloc(1024);
    int* idxPost = (int*)alloc(1024);
    int* idxTok = (int*)alloc(256);
    int* cnt = (int*)alloc(512);

    k_init<<<8, 256, 0, stream>>>(pre, post, trg, idxPre, idxPost, idxTok, cnt, wEff);
    k_clear<<<512, 256, 0, stream>>>((u64*)Pbuf, 16 * 2 * 24576);
    k_weff<<<129, 256, 0, stream>>>(fcHidW, fcHidB, fcOutW, fcOutB, wEff, bEff);
    k_gemm<<<dim3(16, 24), 256, 0, stream>>>(emb, idxPre, 512, WihPre, 512, bihPre, giPre, 1536, 512);
    k_gemm<<<dim3(16, 24), 256, 0, stream>>>(emb, idxPost, 512, WihPost, 512, bihPost, giPost, 1536, 512);
    k_gemm<<<dim3(3, 24), 256, 0, stream>>>(emb, idxTok, 512, WihDec, 1024, bihDec, giE, 1536, 512);
    k_encoder<<<256, 512, 0, stream>>>(giPre, giPost, WhhPre, WhhPost, bhhPre, bhhPost,
                                       encOut, Pbuf);
    k_gemm<<<dim3(32, 8), 256, 0, stream>>>(encOut, nullptr, 512, attnW + 512, 1024, attnB, encProj, 512, 512);
    k_fcenc<<<16, 256, 0, stream>>>(encOut, fcEncW, fcEncB, hBuf);
    k_encdot<<<32, 256, 0, stream>>>(encOut, wEff, encDot);
    k_edot4<<<192, 64, 0, stream>>>(emb, idxTok, wEff, eDot4);
    k_decoder<<<128, 256, 0, stream>>>(encOut, encProj, attnW, attnV, WihDec, WhhDec, bhhDec,
                                       giE, wEff, bEff, eDot4, hBuf, hpBuf, scoresBuf,
                                       gi2, cBuf, cnt);
    k_final<<<192, 256, 0, stream>>>(encDot, cBuf, outp);
}

// Round 3
// 1230.138 us; speedup vs baseline: 3.2781x; 1.3168x over previous
//
#include <hip/hip_runtime.h>
#include <cstdint>

#define B_ 8
#define S_ 128
#define T_ 24
#define E_ 512
#define H_ 512
#define H3_ 1536
#define L_ 256
#define D_ 2048

typedef unsigned long long u64;

__device__ __forceinline__ float fsig(float x) { return 1.0f / (1.0f + __expf(-x)); }
__device__ __forceinline__ float ftanh(float x) { return 1.0f - 2.0f / (1.0f + __expf(2.0f * x)); }
__device__ __forceinline__ float dot4(float4 a, float4 b) {
    return a.x * b.x + a.y * b.y + a.z * b.z + a.w * b.w;
}

// Coherent (LLC-level) 8B atoms: relaxed agent-scope atomics compile to
// global_load/store sc0 sc1 — bypass non-coherent L1/L2, no cache flushes.
__device__ __forceinline__ u64 cohLoadU64(const u64* p) {
    return __hip_atomic_load((u64*)p, __ATOMIC_RELAXED, __HIP_MEMORY_SCOPE_AGENT);
}
__device__ __forceinline__ void cohStoreU64(u64* p, u64 v) {
    __hip_atomic_store(p, v, __ATOMIC_RELAXED, __HIP_MEMORY_SCOPE_AGENT);
}
__device__ __forceinline__ float2 asF2(u64 v) { union { u64 u; float2 f; } x; x.u = v; return x.f; }
__device__ __forceinline__ u64 packF2(float v, float tag) { union { float2 f; u64 u; } x; x.f = make_float2(v, tag); return x.u; }

// ---------------------------------------------------------------------------
__global__ void k_init(const int* __restrict__ pre, const int* __restrict__ post,
                       const int* __restrict__ trg,
                       int* __restrict__ idxPre, int* __restrict__ idxPost,
                       int* __restrict__ idxTok, float* __restrict__ wEff) {
    int tid = blockIdx.x * 256 + threadIdx.x;  // grid 8 x 256 = 2048
    if (tid < 1024) {
        int s = tid >> 3, b = tid & 7;
        idxPre[tid]  = pre[b * S_ + s];
        idxPost[tid] = post[b * S_ + s];
    }
    if (tid < T_ * B_) {
        int t = tid >> 3, b = tid & 7;
        idxTok[tid] = (t == 0) ? pre[b * S_ + (S_ - 1)] : trg[b * T_ + (t - 1)];
    }
    wEff[tid] = 0.f;
}

// Zero the tagged exchange buffers (tags must start != any step tag).
__global__ void k_clear(u64* __restrict__ p, int n) {
    int i = blockIdx.x * 256 + threadIdx.x;
    int stride = gridDim.x * 256;
    for (; i < n; i += stride) p[i] = 0ull;
}

// ---------------------------------------------------------------------------
// Tiled f32 GEMM: C[m][n] = sum_k A[m][k]*B[n][k] + bias[n]
// ---------------------------------------------------------------------------
__global__ __launch_bounds__(256) void k_gemm(
    const float* __restrict__ A, const int* __restrict__ Aidx, int lda,
    const float* __restrict__ Bm, int ldb,
    const float* __restrict__ bias, float* __restrict__ C,
    int N, int K) {
    __shared__ float As[16][68];
    __shared__ float Bs[16][68];
    const int m0 = blockIdx.x * 64, n0 = blockIdx.y * 64;
    const int tid = threadIdx.x;
    const int tm = tid >> 2;
    const int tk = (tid & 3) << 2;
    const int tx = tid & 15, ty = tid >> 4;
    const int am = m0 + tm;
    const float* Arow = A + (size_t)(Aidx ? Aidx[am] : am) * lda;
    const float* Brow = Bm + (size_t)(n0 + tm) * ldb;
    float acc[4][4] = {};
    for (int k0 = 0; k0 < K; k0 += 16) {
        float4 av = *(const float4*)(Arow + k0 + tk);
        float4 bv = *(const float4*)(Brow + k0 + tk);
        __syncthreads();
        As[tk][tm] = av.x; As[tk + 1][tm] = av.y; As[tk + 2][tm] = av.z; As[tk + 3][tm] = av.w;
        Bs[tk][tm] = bv.x; Bs[tk + 1][tm] = bv.y; Bs[tk + 2][tm] = bv.z; Bs[tk + 3][tm] = bv.w;
        __syncthreads();
#pragma unroll
        for (int k = 0; k < 16; ++k) {
            float4 a4 = *(const float4*)(&As[k][ty << 2]);
            float4 b4 = *(const float4*)(&Bs[k][tx << 2]);
            float ar[4] = {a4.x, a4.y, a4.z, a4.w};
            float br[4] = {b4.x, b4.y, b4.z, b4.w};
#pragma unroll
            for (int i = 0; i < 4; ++i)
#pragma unroll
                for (int j = 0; j < 4; ++j) acc[i][j] += ar[i] * br[j];
        }
    }
    float4 bb = bias ? *(const float4*)(bias + n0 + (tx << 2)) : make_float4(0.f, 0.f, 0.f, 0.f);
#pragma unroll
    for (int i = 0; i < 4; ++i) {
        int m = m0 + (ty << 2) + i;
        float4 o;
        o.x = acc[i][0] + bb.x; o.y = acc[i][1] + bb.y;
        o.z = acc[i][2] + bb.z; o.w = acc[i][3] + bb.w;
        *(float4*)(C + (size_t)m * N + n0 + (tx << 2)) = o;
    }
}

// ---------------------------------------------------------------------------
// w_eff = fc_out_W @ fc_hid_W (2048-dot per col), split 128 WGs + f32 atomics.
// b_eff = fc_out_W . fc_hid_b + fc_out_b
// ---------------------------------------------------------------------------
__global__ void k_weff(const float* __restrict__ fcW, const float* __restrict__ fcB,
                       const float* __restrict__ voW, const float* __restrict__ voB,
                       float* __restrict__ wEff, float* __restrict__ bEff) {
    __shared__ float red[256];
    int bx = blockIdx.x;
    if (bx < 128) {
        int cblk = bx & 7, q = bx >> 3;
        int col = cblk * 256 + threadIdx.x;
        int j0 = q * 128;
        float acc = 0.f;
        for (int j = j0; j < j0 + 128; ++j) acc += voW[j] * fcW[(size_t)j * D_ + col];
        atomicAdd(wEff + col, acc);
    } else {
        float p = 0.f;
        for (int j = threadIdx.x; j < D_; j += 256) p += voW[j] * fcB[j];
        red[threadIdx.x] = p;
        __syncthreads();
        for (int s = 128; s > 0; s >>= 1) {
            if (threadIdx.x < s) red[threadIdx.x] += red[threadIdx.x + s];
            __syncthreads();
        }
        if (threadIdx.x == 0) bEff[0] = red[0] + voB[0];
    }
}

// ---------------------------------------------------------------------------
// Encoder scan, k-split chains with TAGGED-DATA sync (unchanged from round 2).
// ---------------------------------------------------------------------------
__global__ __launch_bounds__(512, 2) void k_encoder(
    const float* __restrict__ giPre, const float* __restrict__ giPost,
    const float* __restrict__ WhhPre, const float* __restrict__ WhhPost,
    const float* __restrict__ bhhPre, const float* __restrict__ bhhPost,
    float* __restrict__ encOut, float* __restrict__ Pbuf) {
    const int bx = blockIdx.x;        // 0..255
    const int chain = bx >> 4;        // gr = chain>>3, b = chain&7
    const int p = bx & 15;            // owned h-col block
    const int gr = chain >> 3, b = chain & 7;
    const int kb = p << 5;
    const float* gi  = gr ? giPost : giPre;
    const float* Whh = gr ? WhhPost : WhhPre;
    const float* bhh = gr ? bhhPost : bhhPre;
    const int PH = 24576;                              // slots per phase per chain
    u64* PbU = (u64*)Pbuf + (size_t)chain * (2 * PH);
    const int tid = threadIdx.x;

    __shared__ float hS[32];
    __shared__ float red[96 * 17];
    __shared__ float ghS[96];

    // register-resident weights: rows {tid, 512+tid, 1024+tid}, cols [kb,kb+32)
    float w0[32], w1[32], w2[32];
    {
        const float* r0 = Whh + (size_t)tid * 512 + kb;
        const float* r1 = r0 + (size_t)512 * 512;
        const float* r2 = r1 + (size_t)512 * 512;
#pragma unroll
        for (int kk = 0; kk < 32; ++kk) { w0[kk] = r0[kk]; w1[kk] = r1[kk]; w2[kk] = r2[kk]; }
    }
    float bh0 = 0.f, bh1 = 0.f, bh2 = 0.f;
    if (tid < 32) {
        bh0 = bhh[kb + tid];
        bh1 = bhh[512 + kb + tid];
        bh2 = bhh[1024 + kb + tid];
        hS[tid] = 0.f;
    }
    const int wslot = (tid >> 5) * 1536 + p * 32 + (tid & 31);
    const int rslot = p * 1536 + (tid >> 5) * 32 + (tid & 31);
    __syncthreads();

    for (int t = 0; t < S_; ++t) {
        float4 hv[8];
#pragma unroll
        for (int i = 0; i < 8; ++i) hv[i] = *(const float4*)&hS[i * 4];
        float a0 = 0.f, a1 = 0.f, a2 = 0.f;
#pragma unroll
        for (int i = 0; i < 8; ++i) {
            const float hx = hv[i].x, hy = hv[i].y, hz = hv[i].z, hw = hv[i].w;
            a0 += w0[4 * i] * hx + w0[4 * i + 1] * hy + w0[4 * i + 2] * hz + w0[4 * i + 3] * hw;
            a1 += w1[4 * i] * hx + w1[4 * i + 1] * hy + w1[4 * i + 2] * hz + w1[4 * i + 3] * hw;
            a2 += w2[4 * i] * hx + w2[4 * i + 1] * hy + w2[4 * i + 2] * hz + w2[4 * i + 3] * hw;
        }
        const float tagf = (float)(t + 1);
        u64* Pw = PbU + (t & 1) * PH;
        cohStoreU64(Pw + wslot,        packF2(a0, tagf));
        cohStoreU64(Pw + wslot + 512,  packF2(a1, tagf));
        cohStoreU64(Pw + wslot + 1024, packF2(a2, tagf));
        float g0v = 0.f, g1v = 0.f, g2v = 0.f;
        if (tid < 32) {
            size_t gb = ((size_t)(t << 3) + b) * H3_;
            g0v = gi[gb + kb + tid];
            g1v = gi[gb + 512 + kb + tid];
            g2v = gi[gb + 1024 + kb + tid];
        }
        asm volatile("" ::: "memory");
        const u64* Pr = PbU + (t & 1) * PH;
        float s0 = 0.f, s1 = 0.f, s2 = 0.f;
        bool o0 = false, o1 = false, o2 = false;
        do {
            if (!o0) { float2 f = asF2(cohLoadU64(Pr + rslot));        if (f.y == tagf) { s0 = f.x; o0 = true; } }
            if (!o1) { float2 f = asF2(cohLoadU64(Pr + rslot + 512));  if (f.y == tagf) { s1 = f.x; o1 = true; } }
            if (!o2) { float2 f = asF2(cohLoadU64(Pr + rslot + 1024)); if (f.y == tagf) { s2 = f.x; o2 = true; } }
        } while (!(o0 && o1 && o2));
        {
            int rp = tid >> 5, rc = tid & 31;
            red[(0 * 32 + rc) * 17 + rp] = s0;
            red[(1 * 32 + rc) * 17 + rp] = s1;
            red[(2 * 32 + rc) * 17 + rp] = s2;
        }
        __syncthreads();
        if (tid < 96) {
            int g = tid >> 5, c = tid & 31;
            float s = 0.f;
#pragma unroll
            for (int pp = 0; pp < 16; ++pp) s += red[(g * 32 + c) * 17 + pp];
            ghS[g * 32 + c] = s;
        }
        __syncthreads();
        if (tid < 32) {
            float r = fsig(g0v + ghS[tid] + bh0);
            float z = fsig(g1v + ghS[32 + tid] + bh1);
            float n = ftanh(g2v + r * (ghS[64 + tid] + bh2));
            float h2 = (1.f - z) * n + z * hS[tid];
            hS[tid] = h2;
            encOut[(((size_t)(b << 8) + (gr << 7) + t) << 9) + kb + tid] = h2;
        }
        __syncthreads();
    }
}

// ---------------------------------------------------------------------------
__global__ void k_fcenc(const float* __restrict__ encOut, const float* __restrict__ W,
                        const float* __restrict__ bias, float* __restrict__ h) {
    int o = blockIdx.x * 256 + threadIdx.x;  // grid 16 -> 4096
    int b = o >> 9, j = o & 511;
    const float4* w4 = (const float4*)(W + (size_t)j * 1024);
    const float4* pre4 = (const float4*)(encOut + (((size_t)(b << 8) + 127) << 9));
    const float4* post4 = (const float4*)(encOut + (((size_t)(b << 8) + 255) << 9));
    float acc = bias[j];
    for (int k = 0; k < 128; ++k) acc += dot4(w4[k], pre4[k]);
    for (int k = 0; k < 128; ++k) acc += dot4(w4[128 + k], post4[k]);
    h[o] = ftanh(acc);
}

// enc_dot[b*256+l] = enc_out[b,l,:] . w_eff[0:512]
__global__ void k_encdot(const float* __restrict__ encOut, const float* __restrict__ wEff,
                         float* __restrict__ encDot) {
    int wid = threadIdx.x >> 6, lane = threadIdx.x & 63;
    int gw = blockIdx.x * 4 + wid;  // grid 32 -> 128 waves
    for (int o = gw; o < 2048; o += 128) {
        const float* row = encOut + ((size_t)o << 9);
        float s = 0.f;
        for (int k = lane; k < 512; k += 64) s += row[k] * wEff[k];
        for (int off = 32; off; off >>= 1) s += __shfl_down(s, off);
        if (lane == 0) encDot[o] = s;
    }
}

// eDot4[t*8+b] = emb[tok[t,b]] . w_eff[1536:2048]
__global__ void k_edot4(const float* __restrict__ emb, const int* __restrict__ idxTok,
                        const float* __restrict__ wEff, float* __restrict__ eDot4) {
    int o = blockIdx.x;  // grid 192, block 64
    int lane = threadIdx.x;
    const float* row = emb + (size_t)idxTok[o] * E_;
    const float* w = wEff + 1536;
    float s = 0.f;
    for (int k = lane; k < 512; k += 64) s += row[k] * w[k];
    for (int off = 32; off; off >>= 1) s += __shfl_down(s, off);
    if (lane == 0) eDot4[o] = s;
}

// ---------------------------------------------------------------------------
// Decoder: role-split dataflow, TAGGED-DATA sync, register-resident weights,
// batch-inner (weights loaded ONCE; round-2 streamed ~500KB/WG/step from L2).
// Roles (176 WGs x 512 thr, 1/CU):
//   0..31   GRU: 16 h-cols each; Whh + Wih[:,512:1024] triples in VGPR (96/thr)
//   32..47  HP : 32 attnW_hid rows each (32/thr); h -> hp
//   48..111 SC : (b, 32 l-rows); encProj slice L2-resident; hp -> scores
//   112..175 WT: (b, 64 cols); scores -> softmax (redundant) -> weighted cols
// Critical path/step: h -> hp -> scores -> weighted -> h' = 4 tagged hops.
// Logit partials -> cpart (plain stores), summed off-path by k_csum.
// ---------------------------------------------------------------------------
__global__ __launch_bounds__(512, 2) void k_decoder(
    const float* __restrict__ encOut, const float* __restrict__ encProj,
    const float* __restrict__ attnW, const float* __restrict__ attnV,
    const float* __restrict__ WihDec, const float* __restrict__ WhhDec,
    const float* __restrict__ bhhDec, const float* __restrict__ giE,
    const float* __restrict__ wEff, const float* __restrict__ hBuf,
    u64* __restrict__ hEx, u64* __restrict__ hpEx,
    u64* __restrict__ scEx, u64* __restrict__ wtEx,
    float* __restrict__ cpart) {
    const int tid = threadIdx.x;
    const int bx = blockIdx.x;
    __shared__ float hL[4096];
    __shared__ float xL[4096];
    __shared__ float mS[1408];

    if (bx < 32) {
        // ================= GRU =================
        const int g = bx;
        const int s = tid >> 5, kq = tid & 31;
        const int j = (g << 4) + s;
        float wr[16], wz[16], wn[16], vr[16], vz[16], vn[16];
#pragma unroll
        for (int m = 0; m < 16; ++m) {
            int k = kq + 32 * m;
            wr[m] = WhhDec[(size_t)j * 512 + k];
            wz[m] = WhhDec[(size_t)(512 + j) * 512 + k];
            wn[m] = WhhDec[(size_t)(1024 + j) * 512 + k];
            vr[m] = WihDec[(size_t)j * 1024 + 512 + k];
            vz[m] = WihDec[(size_t)(512 + j) * 1024 + 512 + k];
            vn[m] = WihDec[(size_t)(1024 + j) * 1024 + 512 + k];
        }
        if (tid < 48) mS[1152 + tid] = bhhDec[(tid >> 4) * 512 + (g << 4) + (tid & 15)];
        __syncthreads();
        for (int t = 0; t < T_; ++t) {
            // ---- acquire h (tag t; t==0 from hBuf) ----
            if (t == 0) {
#pragma unroll
                for (int i = 0; i < 8; ++i) hL[tid + 512 * i] = hBuf[tid + 512 * i];
            } else {
                const float tagh = (float)t;
                const u64* src = hEx + (t & 1) * 4096;
                float v[8]; unsigned pend = 255u;
                while (pend) {
#pragma unroll
                    for (int i = 0; i < 8; ++i)
                        if (pend & (1u << i)) {
                            float2 f = asF2(cohLoadU64(src + tid + 512 * i));
                            if (f.y == tagh) { v[i] = f.x; pend &= ~(1u << i); }
                        }
                    if (pend) __builtin_amdgcn_s_sleep(1);
                }
#pragma unroll
                for (int i = 0; i < 8; ++i) hL[tid + 512 * i] = v[i];
            }
            __syncthreads();
            // ---- gh = Whh.h + bhh (own cols, all batches) ----
            for (int b = 0; b < 8; ++b) {
                const float* hb = hL + (b << 9);
                float ar = 0.f, az = 0.f, an = 0.f;
#pragma unroll
                for (int m = 0; m < 16; ++m) {
                    float hv = hb[kq + 32 * m];
                    ar += wr[m] * hv; az += wz[m] * hv; an += wn[m] * hv;
                }
#pragma unroll
                for (int off = 16; off; off >>= 1) {
                    ar += __shfl_xor(ar, off); az += __shfl_xor(az, off); an += __shfl_xor(an, off);
                }
                if (kq == 0) {
                    mS[s * 8 + b]       = ar + mS[1152 + s];
                    mS[128 + s * 8 + b] = az + mS[1168 + s];
                    mS[256 + s * 8 + b] = an + mS[1184 + s];
                }
            }
            // ---- giE prefetch (overlaps the weighted poll) ----
            if (tid < 384) {
                int b = tid / 48, idx = tid % 48, g3 = idx >> 4, ss = idx & 15;
                mS[768 + g3 * 128 + ss * 8 + b] =
                    giE[((size_t)(t << 3) + b) * H3_ + g3 * 512 + (g << 4) + ss];
            }
            // ---- acquire weighted (tag t+1) ----
            {
                const float tagw = (float)(t + 1);
                const u64* src = wtEx + (t & 1) * 4096;
                float v[8]; unsigned pend = 255u;
                while (pend) {
#pragma unroll
                    for (int i = 0; i < 8; ++i)
                        if (pend & (1u << i)) {
                            float2 f = asF2(cohLoadU64(src + tid + 512 * i));
                            if (f.y == tagw) { v[i] = f.x; pend &= ~(1u << i); }
                        }
                    if (pend) __builtin_amdgcn_s_sleep(1);
                }
#pragma unroll
                for (int i = 0; i < 8; ++i) xL[tid + 512 * i] = v[i];
            }
            __syncthreads();
            // ---- giw = Wih_half.weighted ----
            for (int b = 0; b < 8; ++b) {
                const float* wb = xL + (b << 9);
                float ar = 0.f, az = 0.f, an = 0.f;
#pragma unroll
                for (int m = 0; m < 16; ++m) {
                    float wv = wb[kq + 32 * m];
                    ar += vr[m] * wv; az += vz[m] * wv; an += vn[m] * wv;
                }
#pragma unroll
                for (int off = 16; off; off >>= 1) {
                    ar += __shfl_xor(ar, off); az += __shfl_xor(az, off); an += __shfl_xor(an, off);
                }
                if (kq == 0) {
                    mS[384 + s * 8 + b] = ar;
                    mS[512 + s * 8 + b] = az;
                    mS[640 + s * 8 + b] = an;
                }
            }
            __syncthreads();
            // ---- GRU update + h store + logit partial ----
            if (tid < 128) {
                int ss = tid >> 3, b = tid & 7;
                int jj = (g << 4) + ss;
                int o = ss * 8 + b;
                float ghr = mS[o], ghz = mS[128 + o], ghn = mS[256 + o];
                float gir = mS[384 + o] + mS[768 + o];
                float giz = mS[512 + o] + mS[896 + o];
                float gin = mS[640 + o] + mS[1024 + o];
                float r = fsig(gir + ghr), z = fsig(giz + ghz);
                float n = ftanh(gin + r * ghn);
                float h2 = (1.f - z) * n + z * hL[(b << 9) + jj];
                cohStoreU64(hEx + ((t + 1) & 1) * 4096 + (b << 9) + jj, packF2(h2, (float)(t + 1)));
                mS[1200 + o] = h2 * wEff[1024 + jj];
            }
            __syncthreads();
            if (tid < 8) {
                float pc = 0.f;
#pragma unroll
                for (int q = 0; q < 16; ++q) pc += mS[1200 + q * 8 + tid];
                cpart[(tid * T_ + t) * 48 + g] = pc;
            }
            __syncthreads();
        }
    } else if (bx < 48) {
        // ================= HP =================
        const int w = bx - 32;
        const int s = tid >> 5, kq = tid & 31;
        const int r0 = (w << 5) + s, r1 = r0 + 16;
        float wa[16], wb[16];
#pragma unroll
        for (int m = 0; m < 16; ++m) {
            int k = kq + 32 * m;
            wa[m] = attnW[(size_t)r0 * 1024 + k];
            wb[m] = attnW[(size_t)r1 * 1024 + k];
        }
        for (int t = 0; t < T_; ++t) {
            if (t == 0) {
#pragma unroll
                for (int i = 0; i < 8; ++i) hL[tid + 512 * i] = hBuf[tid + 512 * i];
            } else {
                const float tagh = (float)t;
                const u64* src = hEx + (t & 1) * 4096;
                float v[8]; unsigned pend = 255u;
                while (pend) {
#pragma unroll
                    for (int i = 0; i < 8; ++i)
                        if (pend & (1u << i)) {
                            float2 f = asF2(cohLoadU64(src + tid + 512 * i));
                            if (f.y == tagh) { v[i] = f.x; pend &= ~(1u << i); }
                        }
                    if (pend) __builtin_amdgcn_s_sleep(1);
                }
#pragma unroll
                for (int i = 0; i < 8; ++i) hL[tid + 512 * i] = v[i];
            }
            __syncthreads();
            const float tago = (float)(t + 1);
            u64* dst = hpEx + (t & 1) * 4096;
            for (int b = 0; b < 8; ++b) {
                const float* hb = hL + (b << 9);
                float aa = 0.f, ab = 0.f;
#pragma unroll
                for (int m = 0; m < 16; ++m) {
                    float hv = hb[kq + 32 * m];
                    aa += wa[m] * hv; ab += wb[m] * hv;
                }
#pragma unroll
                for (int off = 16; off; off >>= 1) { aa += __shfl_xor(aa, off); ab += __shfl_xor(ab, off); }
                if (kq == 0) {
                    cohStoreU64(dst + (b << 9) + r0, packF2(aa, tago));
                    cohStoreU64(dst + (b << 9) + r1, packF2(ab, tago));
                }
            }
            __syncthreads();
        }
    } else if (bx < 112) {
        // ================= SC =================
        const int id = bx - 48;
        const int b = id >> 3, lq = id & 7;
        const int kq = tid & 63, lg = tid >> 6;
        for (int t = 0; t < T_; ++t) {
            const float tagi = (float)(t + 1);
            {
                const u64* src = hpEx + (t & 1) * 4096 + (b << 9);
                float2 f;
                for (;;) {
                    f = asF2(cohLoadU64(src + tid));
                    if (f.y == tagi) break;
                    __builtin_amdgcn_s_sleep(1);
                }
                hL[tid] = f.x;
            }
            __syncthreads();
            u64* dst = scEx + (t & 1) * 2048 + (b << 8);
#pragma unroll
            for (int i = 0; i < 4; ++i) {
                int l = (lq << 5) + lg + (i << 3);
                const float* ep = encProj + (((size_t)(b << 8) + l) << 9);
                float sc = 0.f;
#pragma unroll
                for (int m = 0; m < 8; ++m) {
                    int k = kq + (m << 6);
                    sc += attnV[k] * ftanh(ep[k] + hL[k]);
                }
#pragma unroll
                for (int off = 32; off; off >>= 1) sc += __shfl_xor(sc, off);
                if (kq == 0) cohStoreU64(dst + l, packF2(sc, tagi));
            }
            __syncthreads();
        }
    } else if (bx < 176) {
        // ================= WT =================
        const int id = bx - 112;
        const int b = id >> 3, cq = id & 7;
        const int c = tid & 63, lg = tid >> 6;
        for (int t = 0; t < T_; ++t) {
            const float tagi = (float)(t + 1);
            if (tid < 256) {
                const u64* src = scEx + (t & 1) * 2048 + (b << 8);
                float2 f;
                for (;;) {
                    f = asF2(cohLoadU64(src + tid));
                    if (f.y == tagi) break;
                    __builtin_amdgcn_s_sleep(1);
                }
                mS[tid] = f.x;
            }
            __syncthreads();
            if (tid < 256) mS[256 + tid] = mS[tid];
            __syncthreads();
            for (int st = 128; st; st >>= 1) {
                if (tid < st) mS[256 + tid] = fmaxf(mS[256 + tid], mS[256 + tid + st]);
                __syncthreads();
            }
            float mx = mS[256];
            __syncthreads();
            if (tid < 256) { float ex = __expf(mS[tid] - mx); mS[tid] = ex; mS[256 + tid] = ex; }
            __syncthreads();
            for (int st = 128; st; st >>= 1) {
                if (tid < st) mS[256 + tid] += mS[256 + tid + st];
                __syncthreads();
            }
            float inv = 1.f / mS[256];
            // weighted cols (complete, no cross-WG reduce)
            float acc = 0.f;
            const float* eb = encOut + (((size_t)(b << 8)) << 9) + (cq << 6) + c;
#pragma unroll
            for (int m = 0; m < 32; ++m) {
                int l = lg + (m << 3);
                acc += mS[l] * eb[(size_t)l << 9];
            }
            mS[512 + lg * 64 + c] = acc;
            __syncthreads();
            if (tid < 64) {
                float wv = 0.f;
#pragma unroll
                for (int q = 0; q < 8; ++q) wv += mS[512 + q * 64 + tid];
                wv *= inv;
                cohStoreU64(wtEx + (t & 1) * 4096 + (b << 9) + (cq << 6) + tid, packF2(wv, tagi));
                mS[1024 + tid] = wv * wEff[512 + (cq << 6) + tid];
            }
            __syncthreads();
            if (tid == 0) {
                float pc = 0.f;
                for (int q = 0; q < 64; ++q) pc += mS[1024 + q];
                cpart[(b * T_ + t) * 48 + 32 + cq] = pc;
            }
            __syncthreads();
        }
    }
}

// c[b,t] = eDot4 + bEff + sum of 40 partials (32 GRU + 8 WT)
__global__ void k_csum(const float* __restrict__ cpart, const float* __restrict__ eDot4,
                       const float* __restrict__ bEff, float* __restrict__ cBuf) {
    int tid = threadIdx.x;
    if (tid < 192) {
        int b = tid / 24, t = tid % 24;
        float acc = eDot4[t * 8 + b] + bEff[0];
        const float* p = cpart + (b * T_ + t) * 48;
#pragma unroll
        for (int k = 0; k < 40; ++k) acc += p[k];
        cBuf[b * T_ + t] = acc;
    }
}

// out[b,t,l-part] = enc_dot[b,l] + c[b,t]
__global__ void k_final(const float* __restrict__ encDot, const float* __restrict__ c,
                        float* __restrict__ out) {
    int idx = blockIdx.x * 256 + threadIdx.x;  // grid 192 -> 49152
    const int half = B_ * T_ * S_;
    int w = idx < half ? idx : idx - half;
    int b = w / (T_ * S_);
    int r = w % (T_ * S_);
    int t = r / S_, sidx = r % S_;
    int l = (idx < half) ? sidx : (S_ + sidx);
    out[idx] = encDot[b * L_ + l] + c[b * T_ + t];
}

// ---------------------------------------------------------------------------
extern "C" void kernel_launch(void* const* d_in, const int* in_sizes, int n_in,
                              void* d_out, int out_size, void* d_ws, size_t ws_size,
                              hipStream_t stream) {
    const int* pre = (const int*)d_in[0];
    const int* post = (const int*)d_in[1];
    const int* trg = (const int*)d_in[2];
    const float* emb = (const float*)d_in[3];
    const float* WihPre = (const float*)d_in[4];
    const float* WhhPre = (const float*)d_in[5];
    const float* bihPre = (const float*)d_in[6];
    const float* bhhPre = (const float*)d_in[7];
    const float* WihPost = (const float*)d_in[8];
    const float* WhhPost = (const float*)d_in[9];
    const float* bihPost = (const float*)d_in[10];
    const float* bhhPost = (const float*)d_in[11];
    const float* fcEncW = (const float*)d_in[12];
    const float* fcEncB = (const float*)d_in[13];
    const float* attnW = (const float*)d_in[14];
    const float* attnB = (const float*)d_in[15];
    const float* attnV = (const float*)d_in[16];
    const float* WihDec = (const float*)d_in[17];
    const float* WhhDec = (const float*)d_in[18];
    const float* bihDec = (const float*)d_in[19];
    const float* bhhDec = (const float*)d_in[20];
    const float* fcHidW = (const float*)d_in[21];
    const float* fcHidB = (const float*)d_in[22];
    const float* fcOutW = (const float*)d_in[23];
    const float* fcOutB = (const float*)d_in[24];
    float* outp = (float*)d_out;

    float* base = (float*)d_ws;
    size_t off = 0;
    auto alloc = [&](size_t n) {
        float* p = base + off;
        off += (n + 63) & ~(size_t)63;
        return p;
    };
    float* giPre = alloc(1024 * 1536);
    float* giPost = alloc(1024 * 1536);
    float* giE = alloc(192 * 1536);
    float* encOut = alloc(8 * 256 * 512);
    float* encProj = alloc(8 * 256 * 512);
    float* wEff = alloc(2048);
    float* bEff = alloc(64);
    float* encDot = alloc(2048);
    float* eDot4 = alloc(256);
    float* hBuf = alloc(4096);
    float* cBuf = alloc(256);
    float* Pbuf = alloc(2 * 16 * 24576 * 2);  // encoder exchange (u64 slots)
    float* hExF = alloc(16384);               // 2 x 4096 u64
    float* hpExF = alloc(16384);              // 2 x 4096 u64
    float* scExF = alloc(8192);               // 2 x 2048 u64
    float* wtExF = alloc(16384);              // 2 x 4096 u64
    float* cpart = alloc(8 * 24 * 48);
    int* idxPre = (int*)alloc(1024);
    int* idxPost = (int*)alloc(1024);
    int* idxTok = (int*)alloc(256);

    k_init<<<8, 256, 0, stream>>>(pre, post, trg, idxPre, idxPost, idxTok, wEff);
    // Pbuf + hEx + hpEx + scEx + wtEx are contiguous: one clear.
    k_clear<<<512, 256, 0, stream>>>((u64*)Pbuf, 786432 + 28672);
    k_weff<<<129, 256, 0, stream>>>(fcHidW, fcHidB, fcOutW, fcOutB, wEff, bEff);
    k_gemm<<<dim3(16, 24), 256, 0, stream>>>(emb, idxPre, 512, WihPre, 512, bihPre, giPre, 1536, 512);
    k_gemm<<<dim3(16, 24), 256, 0, stream>>>(emb, idxPost, 512, WihPost, 512, bihPost, giPost, 1536, 512);
    k_gemm<<<dim3(3, 24), 256, 0, stream>>>(emb, idxTok, 512, WihDec, 1024, bihDec, giE, 1536, 512);
    k_encoder<<<256, 512, 0, stream>>>(giPre, giPost, WhhPre, WhhPost, bhhPre, bhhPost,
                                       encOut, Pbuf);
    k_gemm<<<dim3(32, 8), 256, 0, stream>>>(encOut, nullptr, 512, attnW + 512, 1024, attnB, encProj, 512, 512);
    k_fcenc<<<16, 256, 0, stream>>>(encOut, fcEncW, fcEncB, hBuf);
    k_encdot<<<32, 256, 0, stream>>>(encOut, wEff, encDot);
    k_edot4<<<192, 64, 0, stream>>>(emb, idxTok, wEff, eDot4);
    k_decoder<<<176, 512, 0, stream>>>(encOut, encProj, attnW, attnV, WihDec, WhhDec, bhhDec,
                                       giE, wEff, hBuf, (u64*)hExF, (u64*)hpExF,
                                       (u64*)scExF, (u64*)wtExF, cpart);
    k_csum<<<1, 256, 0, stream>>>(cpart, eDot4, bEff, cBuf);
    k_final<<<192, 256, 0, stream>>>(encDot, cBuf, outp);
}

// Round 4
// 1023.042 us; speedup vs baseline: 3.9417x; 1.2024x over previous
//
#include <hip/hip_runtime.h>
#include <cstdint>

#define B_ 8
#define S_ 128
#define T_ 24
#define E_ 512
#define H_ 512
#define H3_ 1536
#define L_ 256
#define D_ 2048

typedef unsigned long long u64;

__device__ __forceinline__ float fsig(float x) { return 1.0f / (1.0f + __expf(-x)); }
__device__ __forceinline__ float ftanh(float x) { return 1.0f - 2.0f / (1.0f + __expf(2.0f * x)); }
__device__ __forceinline__ float dot4(float4 a, float4 b) {
    return a.x * b.x + a.y * b.y + a.z * b.z + a.w * b.w;
}

// Coherent (LLC-level) 8B atoms: relaxed agent-scope atomics compile to
// global_load/store sc0 sc1 — bypass non-coherent L1/L2, no cache flushes.
__device__ __forceinline__ u64 cohLoadU64(const u64* p) {
    return __hip_atomic_load((u64*)p, __ATOMIC_RELAXED, __HIP_MEMORY_SCOPE_AGENT);
}
__device__ __forceinline__ void cohStoreU64(u64* p, u64 v) {
    __hip_atomic_store(p, v, __ATOMIC_RELAXED, __HIP_MEMORY_SCOPE_AGENT);
}
__device__ __forceinline__ float2 asF2(u64 v) { union { u64 u; float2 f; } x; x.u = v; return x.f; }
__device__ __forceinline__ u64 packF2(float v, float tag) { union { float2 f; u64 u; } x; x.f = make_float2(v, tag); return x.u; }

// ---------------------------------------------------------------------------
__global__ void k_init(const int* __restrict__ pre, const int* __restrict__ post,
                       const int* __restrict__ trg,
                       int* __restrict__ idxPre, int* __restrict__ idxPost,
                       int* __restrict__ idxTok, float* __restrict__ wEff) {
    int tid = blockIdx.x * 256 + threadIdx.x;  // grid 8 x 256 = 2048
    if (tid < 1024) {
        int s = tid >> 3, b = tid & 7;
        idxPre[tid]  = pre[b * S_ + s];
        idxPost[tid] = post[b * S_ + s];
    }
    if (tid < T_ * B_) {
        int t = tid >> 3, b = tid & 7;
        idxTok[tid] = (t == 0) ? pre[b * S_ + (S_ - 1)] : trg[b * T_ + (t - 1)];
    }
    wEff[tid] = 0.f;
}

// Zero the tagged exchange buffers (tags must start != any step tag).
__global__ void k_clear(u64* __restrict__ p, int n) {
    int i = blockIdx.x * 256 + threadIdx.x;
    int stride = gridDim.x * 256;
    for (; i < n; i += stride) p[i] = 0ull;
}

// ---------------------------------------------------------------------------
// Tiled f32 GEMM: C[m][n] = sum_k A[m][k]*B[n][k] + bias[n]
// ---------------------------------------------------------------------------
__global__ __launch_bounds__(256) void k_gemm(
    const float* __restrict__ A, const int* __restrict__ Aidx, int lda,
    const float* __restrict__ Bm, int ldb,
    const float* __restrict__ bias, float* __restrict__ C,
    int N, int K) {
    __shared__ float As[16][68];
    __shared__ float Bs[16][68];
    const int m0 = blockIdx.x * 64, n0 = blockIdx.y * 64;
    const int tid = threadIdx.x;
    const int tm = tid >> 2;
    const int tk = (tid & 3) << 2;
    const int tx = tid & 15, ty = tid >> 4;
    const int am = m0 + tm;
    const float* Arow = A + (size_t)(Aidx ? Aidx[am] : am) * lda;
    const float* Brow = Bm + (size_t)(n0 + tm) * ldb;
    float acc[4][4] = {};
    for (int k0 = 0; k0 < K; k0 += 16) {
        float4 av = *(const float4*)(Arow + k0 + tk);
        float4 bv = *(const float4*)(Brow + k0 + tk);
        __syncthreads();
        As[tk][tm] = av.x; As[tk + 1][tm] = av.y; As[tk + 2][tm] = av.z; As[tk + 3][tm] = av.w;
        Bs[tk][tm] = bv.x; Bs[tk + 1][tm] = bv.y; Bs[tk + 2][tm] = bv.z; Bs[tk + 3][tm] = bv.w;
        __syncthreads();
#pragma unroll
        for (int k = 0; k < 16; ++k) {
            float4 a4 = *(const float4*)(&As[k][ty << 2]);
            float4 b4 = *(const float4*)(&Bs[k][tx << 2]);
            float ar[4] = {a4.x, a4.y, a4.z, a4.w};
            float br[4] = {b4.x, b4.y, b4.z, b4.w};
#pragma unroll
            for (int i = 0; i < 4; ++i)
#pragma unroll
                for (int j = 0; j < 4; ++j) acc[i][j] += ar[i] * br[j];
        }
    }
    float4 bb = bias ? *(const float4*)(bias + n0 + (tx << 2)) : make_float4(0.f, 0.f, 0.f, 0.f);
#pragma unroll
    for (int i = 0; i < 4; ++i) {
        int m = m0 + (ty << 2) + i;
        float4 o;
        o.x = acc[i][0] + bb.x; o.y = acc[i][1] + bb.y;
        o.z = acc[i][2] + bb.z; o.w = acc[i][3] + bb.w;
        *(float4*)(C + (size_t)m * N + n0 + (tx << 2)) = o;
    }
}

// ---------------------------------------------------------------------------
// w_eff = fc_out_W @ fc_hid_W (2048-dot per col), split 128 WGs + f32 atomics.
// b_eff = fc_out_W . fc_hid_b + fc_out_b
// ---------------------------------------------------------------------------
__global__ void k_weff(const float* __restrict__ fcW, const float* __restrict__ fcB,
                       const float* __restrict__ voW, const float* __restrict__ voB,
                       float* __restrict__ wEff, float* __restrict__ bEff) {
    __shared__ float red[256];
    int bx = blockIdx.x;
    if (bx < 128) {
        int cblk = bx & 7, q = bx >> 3;
        int col = cblk * 256 + threadIdx.x;
        int j0 = q * 128;
        float acc = 0.f;
        for (int j = j0; j < j0 + 128; ++j) acc += voW[j] * fcW[(size_t)j * D_ + col];
        atomicAdd(wEff + col, acc);
    } else {
        float p = 0.f;
        for (int j = threadIdx.x; j < D_; j += 256) p += voW[j] * fcB[j];
        red[threadIdx.x] = p;
        __syncthreads();
        for (int s = 128; s > 0; s >>= 1) {
            if (threadIdx.x < s) red[threadIdx.x] += red[threadIdx.x + s];
            __syncthreads();
        }
        if (threadIdx.x == 0) bEff[0] = red[0] + voB[0];
    }
}

// ---------------------------------------------------------------------------
// Encoder scan, COL-SPLIT with h-broadcast tagged sync.
// 16 chains x 16 WGs; WG p owns h-cols [32p,32p+32). Thread (c,l): col c of
// the block, lane l of 16; holds Whh rows {j,512+j,1024+j} segment
// [32l,32l+32) in VGPRs (96 floats). Per step: poll ONE tagged u64 (h[tid]
// of the chain, single LLC round trip, coalesced+broadcast) -> LDS (stride-36
// padded) -> 96 reg FMA -> width-16 shfl reduce -> lane0 gates -> publish 32
// tagged h2. Exchange volume 4KB/chain/step (round-3 k-split: 196KB and
// 3 SERIAL poll round trips -> ~1.8 TB/s LLC traffic, the encoder killer).
// ---------------------------------------------------------------------------
__global__ __launch_bounds__(512, 2) void k_encoder(
    const float* __restrict__ giPre, const float* __restrict__ giPost,
    const float* __restrict__ WhhPre, const float* __restrict__ WhhPost,
    const float* __restrict__ bhhPre, const float* __restrict__ bhhPost,
    float* __restrict__ encOut, u64* __restrict__ encEx) {
    const int bx = blockIdx.x;        // 0..255
    const int chain = bx >> 4;        // gr = chain>>3, b = chain&7
    const int p = bx & 15;            // owned col block
    const int gr = chain >> 3, b = chain & 7;
    const int kb = p << 5;
    const int tid = threadIdx.x;
    const int c = tid >> 4, l = tid & 15;
    const int j = kb + c;             // this thread's output col
    const float* gi  = gr ? giPost : giPre;
    const float* Whh = gr ? WhhPost : WhhPre;
    const float* bhh = gr ? bhhPost : bhhPre;
    u64* ex0 = encEx + chain * 512;   // + parity*8192 (u64 slots)

    __shared__ float hS[576];         // [16 segs][36] padded (bank spread)

    // register-resident weights: rows {j, 512+j, 1024+j}, elems [32l, 32l+32)
    float wr[32], wz[32], wn[32];
    {
        const float* r0 = Whh + (size_t)j * 512 + l * 32;
        const float* r1 = r0 + 512 * 512;
        const float* r2 = r1 + 512 * 512;
#pragma unroll
        for (int m = 0; m < 32; ++m) { wr[m] = r0[m]; wz[m] = r1[m]; wn[m] = r2[m]; }
    }
    const float bh0 = bhh[j], bh1 = bhh[512 + j], bh2 = bhh[1024 + j];

    for (int t = 0; t < S_; ++t) {
        // gi prefetch (independent of h, issued before the poll)
        float g0 = 0.f, g1 = 0.f, g2 = 0.f;
        if (l == 0) {
            size_t gb = ((size_t)(t << 3) + b) * H3_;
            g0 = gi[gb + j]; g1 = gi[gb + 512 + j]; g2 = gi[gb + 1024 + j];
        }
        // acquire h: each thread polls exactly ONE slot (col tid)
        if (t == 0) {
            hS[(tid >> 5) * 36 + (tid & 31)] = 0.f;
        } else {
            const float tag = (float)t;
            const u64* src = ex0 + (t & 1) * 8192;
            float v;
            for (;;) {
                float2 f = asF2(cohLoadU64(src + tid));
                if (f.y == tag) { v = f.x; break; }
                __builtin_amdgcn_s_sleep(1);
            }
            hS[(tid >> 5) * 36 + (tid & 31)] = v;
        }
        __syncthreads();
        // full-row dot: weights in VGPR, h from LDS
        const float* hseg = hS + l * 36;
        float a0 = 0.f, a1 = 0.f, a2 = 0.f;
#pragma unroll
        for (int m = 0; m < 32; ++m) {
            float hv = hseg[m];
            a0 += wr[m] * hv; a1 += wz[m] * hv; a2 += wn[m] * hv;
        }
#pragma unroll
        for (int off = 8; off; off >>= 1) {
            a0 += __shfl_xor(a0, off, 16);
            a1 += __shfl_xor(a1, off, 16);
            a2 += __shfl_xor(a2, off, 16);
        }
        if (l == 0) {
            float r = fsig(g0 + a0 + bh0);
            float z = fsig(g1 + a1 + bh1);
            float n = ftanh(g2 + r * (a2 + bh2));
            float h2 = (1.f - z) * n + z * hS[p * 36 + c];
            cohStoreU64(ex0 + ((t + 1) & 1) * 8192 + j, packF2(h2, (float)(t + 1)));
            encOut[(((size_t)(b << 8) + (gr << 7) + t) << 9) + j] = h2;
        }
        __syncthreads();
    }
}

// ---------------------------------------------------------------------------
__global__ void k_fcenc(const float* __restrict__ encOut, const float* __restrict__ W,
                        const float* __restrict__ bias, float* __restrict__ h) {
    int o = blockIdx.x * 256 + threadIdx.x;  // grid 16 -> 4096
    int b = o >> 9, j = o & 511;
    const float4* w4 = (const float4*)(W + (size_t)j * 1024);
    const float4* pre4 = (const float4*)(encOut + (((size_t)(b << 8) + 127) << 9));
    const float4* post4 = (const float4*)(encOut + (((size_t)(b << 8) + 255) << 9));
    float acc = bias[j];
    for (int k = 0; k < 128; ++k) acc += dot4(w4[k], pre4[k]);
    for (int k = 0; k < 128; ++k) acc += dot4(w4[128 + k], post4[k]);
    h[o] = ftanh(acc);
}

// enc_dot[b*256+l] = enc_out[b,l,:] . w_eff[0:512]
__global__ void k_encdot(const float* __restrict__ encOut, const float* __restrict__ wEff,
                         float* __restrict__ encDot) {
    int wid = threadIdx.x >> 6, lane = threadIdx.x & 63;
    int gw = blockIdx.x * 4 + wid;  // grid 32 -> 128 waves
    for (int o = gw; o < 2048; o += 128) {
        const float* row = encOut + ((size_t)o << 9);
        float s = 0.f;
        for (int k = lane; k < 512; k += 64) s += row[k] * wEff[k];
        for (int off = 32; off; off >>= 1) s += __shfl_down(s, off);
        if (lane == 0) encDot[o] = s;
    }
}

// eDot4[t*8+b] = emb[tok[t,b]] . w_eff[1536:2048]
__global__ void k_edot4(const float* __restrict__ emb, const int* __restrict__ idxTok,
                        const float* __restrict__ wEff, float* __restrict__ eDot4) {
    int o = blockIdx.x;  // grid 192, block 64
    int lane = threadIdx.x;
    const float* row = emb + (size_t)idxTok[o] * E_;
    const float* w = wEff + 1536;
    float s = 0.f;
    for (int k = lane; k < 512; k += 64) s += row[k] * w[k];
    for (int off = 32; off; off >>= 1) s += __shfl_down(s, off);
    if (lane == 0) eDot4[o] = s;
}

// ---------------------------------------------------------------------------
// Decoder: role-split dataflow, TAGGED-DATA sync, register-resident weights.
// Round-4 fix: BATCHED polls — issue all 8 loads, then check all tags, retry
// the group (round-3's per-bit if(pend) chain serialized up to 8 dependent
// LLC round trips per acquire ≈ 5-6 us; now 1 round trip per acquire).
// ---------------------------------------------------------------------------
__global__ __launch_bounds__(512, 2) void k_decoder(
    const float* __restrict__ encOut, const float* __restrict__ encProj,
    const float* __restrict__ attnW, const float* __restrict__ attnV,
    const float* __restrict__ WihDec, const float* __restrict__ WhhDec,
    const float* __restrict__ bhhDec, const float* __restrict__ giE,
    const float* __restrict__ wEff, const float* __restrict__ hBuf,
    u64* __restrict__ hEx, u64* __restrict__ hpEx,
    u64* __restrict__ scEx, u64* __restrict__ wtEx,
    float* __restrict__ cpart) {
    const int tid = threadIdx.x;
    const int bx = blockIdx.x;
    __shared__ float hL[4096];
    __shared__ float xL[4096];
    __shared__ float mS[1408];

    if (bx < 32) {
        // ================= GRU =================
        const int g = bx;
        const int s = tid >> 5, kq = tid & 31;
        const int j = (g << 4) + s;
        float wr[16], wz[16], wn[16], vr[16], vz[16], vn[16];
#pragma unroll
        for (int m = 0; m < 16; ++m) {
            int k = kq + 32 * m;
            wr[m] = WhhDec[(size_t)j * 512 + k];
            wz[m] = WhhDec[(size_t)(512 + j) * 512 + k];
            wn[m] = WhhDec[(size_t)(1024 + j) * 512 + k];
            vr[m] = WihDec[(size_t)j * 1024 + 512 + k];
            vz[m] = WihDec[(size_t)(512 + j) * 1024 + 512 + k];
            vn[m] = WihDec[(size_t)(1024 + j) * 1024 + 512 + k];
        }
        if (tid < 48) mS[1152 + tid] = bhhDec[(tid >> 4) * 512 + (g << 4) + (tid & 15)];
        __syncthreads();
        for (int t = 0; t < T_; ++t) {
            // ---- acquire h (tag t; t==0 from hBuf); batched poll ----
            if (t == 0) {
#pragma unroll
                for (int i = 0; i < 8; ++i) hL[tid + 512 * i] = hBuf[tid + 512 * i];
            } else {
                const float tagh = (float)t;
                const u64* src = hEx + (t & 1) * 4096;
                float v[8];
                for (;;) {
                    u64 rr[8];
#pragma unroll
                    for (int i = 0; i < 8; ++i) rr[i] = cohLoadU64(src + tid + 512 * i);
                    bool ok = true;
#pragma unroll
                    for (int i = 0; i < 8; ++i) { float2 f = asF2(rr[i]); v[i] = f.x; ok &= (f.y == tagh); }
                    if (ok) break;
                    __builtin_amdgcn_s_sleep(1);
                }
#pragma unroll
                for (int i = 0; i < 8; ++i) hL[tid + 512 * i] = v[i];
            }
            __syncthreads();
            // ---- gh = Whh.h + bhh (own cols, all batches) ----
            for (int b = 0; b < 8; ++b) {
                const float* hb = hL + (b << 9);
                float ar = 0.f, az = 0.f, an = 0.f;
#pragma unroll
                for (int m = 0; m < 16; ++m) {
                    float hv = hb[kq + 32 * m];
                    ar += wr[m] * hv; az += wz[m] * hv; an += wn[m] * hv;
                }
#pragma unroll
                for (int off = 16; off; off >>= 1) {
                    ar += __shfl_xor(ar, off); az += __shfl_xor(az, off); an += __shfl_xor(an, off);
                }
                if (kq == 0) {
                    mS[s * 8 + b]       = ar + mS[1152 + s];
                    mS[128 + s * 8 + b] = az + mS[1168 + s];
                    mS[256 + s * 8 + b] = an + mS[1184 + s];
                }
            }
            // ---- giE prefetch (overlaps the weighted poll) ----
            if (tid < 384) {
                int b = tid / 48, idx = tid % 48, g3 = idx >> 4, ss = idx & 15;
                mS[768 + g3 * 128 + ss * 8 + b] =
                    giE[((size_t)(t << 3) + b) * H3_ + g3 * 512 + (g << 4) + ss];
            }
            // ---- acquire weighted (tag t+1); batched poll ----
            {
                const float tagw = (float)(t + 1);
                const u64* src = wtEx + (t & 1) * 4096;
                float v[8];
                for (;;) {
                    u64 rr[8];
#pragma unroll
                    for (int i = 0; i < 8; ++i) rr[i] = cohLoadU64(src + tid + 512 * i);
                    bool ok = true;
#pragma unroll
                    for (int i = 0; i < 8; ++i) { float2 f = asF2(rr[i]); v[i] = f.x; ok &= (f.y == tagw); }
                    if (ok) break;
                    __builtin_amdgcn_s_sleep(1);
                }
#pragma unroll
                for (int i = 0; i < 8; ++i) xL[tid + 512 * i] = v[i];
            }
            __syncthreads();
            // ---- giw = Wih_half.weighted ----
            for (int b = 0; b < 8; ++b) {
                const float* wb = xL + (b << 9);
                float ar = 0.f, az = 0.f, an = 0.f;
#pragma unroll
                for (int m = 0; m < 16; ++m) {
                    float wv = wb[kq + 32 * m];
                    ar += vr[m] * wv; az += vz[m] * wv; an += vn[m] * wv;
                }
#pragma unroll
                for (int off = 16; off; off >>= 1) {
                    ar += __shfl_xor(ar, off); az += __shfl_xor(az, off); an += __shfl_xor(an, off);
                }
                if (kq == 0) {
                    mS[384 + s * 8 + b] = ar;
                    mS[512 + s * 8 + b] = az;
                    mS[640 + s * 8 + b] = an;
                }
            }
            __syncthreads();
            // ---- GRU update + h store + logit partial ----
            if (tid < 128) {
                int ss = tid >> 3, b = tid & 7;
                int jj = (g << 4) + ss;
                int o = ss * 8 + b;
                float ghr = mS[o], ghz = mS[128 + o], ghn = mS[256 + o];
                float gir = mS[384 + o] + mS[768 + o];
                float giz = mS[512 + o] + mS[896 + o];
                float gin = mS[640 + o] + mS[1024 + o];
                float r = fsig(gir + ghr), z = fsig(giz + ghz);
                float n = ftanh(gin + r * ghn);
                float h2 = (1.f - z) * n + z * hL[(b << 9) + jj];
                cohStoreU64(hEx + ((t + 1) & 1) * 4096 + (b << 9) + jj, packF2(h2, (float)(t + 1)));
                mS[1200 + o] = h2 * wEff[1024 + jj];
            }
            __syncthreads();
            if (tid < 8) {
                float pc = 0.f;
#pragma unroll
                for (int q = 0; q < 16; ++q) pc += mS[1200 + q * 8 + tid];
                cpart[(tid * T_ + t) * 48 + g] = pc;
            }
            __syncthreads();
        }
    } else if (bx < 48) {
        // ================= HP =================
        const int w = bx - 32;
        const int s = tid >> 5, kq = tid & 31;
        const int r0 = (w << 5) + s, r1 = r0 + 16;
        float wa[16], wb[16];
#pragma unroll
        for (int m = 0; m < 16; ++m) {
            int k = kq + 32 * m;
            wa[m] = attnW[(size_t)r0 * 1024 + k];
            wb[m] = attnW[(size_t)r1 * 1024 + k];
        }
        for (int t = 0; t < T_; ++t) {
            if (t == 0) {
#pragma unroll
                for (int i = 0; i < 8; ++i) hL[tid + 512 * i] = hBuf[tid + 512 * i];
            } else {
                const float tagh = (float)t;
                const u64* src = hEx + (t & 1) * 4096;
                float v[8];
                for (;;) {
                    u64 rr[8];
#pragma unroll
                    for (int i = 0; i < 8; ++i) rr[i] = cohLoadU64(src + tid + 512 * i);
                    bool ok = true;
#pragma unroll
                    for (int i = 0; i < 8; ++i) { float2 f = asF2(rr[i]); v[i] = f.x; ok &= (f.y == tagh); }
                    if (ok) break;
                    __builtin_amdgcn_s_sleep(1);
                }
#pragma unroll
                for (int i = 0; i < 8; ++i) hL[tid + 512 * i] = v[i];
            }
            __syncthreads();
            const float tago = (float)(t + 1);
            u64* dst = hpEx + (t & 1) * 4096;
            for (int b = 0; b < 8; ++b) {
                const float* hb = hL + (b << 9);
                float aa = 0.f, ab = 0.f;
#pragma unroll
                for (int m = 0; m < 16; ++m) {
                    float hv = hb[kq + 32 * m];
                    aa += wa[m] * hv; ab += wb[m] * hv;
                }
#pragma unroll
                for (int off = 16; off; off >>= 1) { aa += __shfl_xor(aa, off); ab += __shfl_xor(ab, off); }
                if (kq == 0) {
                    cohStoreU64(dst + (b << 9) + r0, packF2(aa, tago));
                    cohStoreU64(dst + (b << 9) + r1, packF2(ab, tago));
                }
            }
            __syncthreads();
        }
    } else if (bx < 112) {
        // ================= SC =================
        const int id = bx - 48;
        const int b = id >> 3, lq = id & 7;
        const int kq = tid & 63, lg = tid >> 6;
        for (int t = 0; t < T_; ++t) {
            const float tagi = (float)(t + 1);
            {
                const u64* src = hpEx + (t & 1) * 4096 + (b << 9);
                float2 f;
                for (;;) {
                    f = asF2(cohLoadU64(src + tid));
                    if (f.y == tagi) break;
                    __builtin_amdgcn_s_sleep(1);
                }
                hL[tid] = f.x;
            }
            __syncthreads();
            u64* dst = scEx + (t & 1) * 2048 + (b << 8);
#pragma unroll
            for (int i = 0; i < 4; ++i) {
                int l = (lq << 5) + lg + (i << 3);
                const float* ep = encProj + (((size_t)(b << 8) + l) << 9);
                float sc = 0.f;
#pragma unroll
                for (int m = 0; m < 8; ++m) {
                    int k = kq + (m << 6);
                    sc += attnV[k] * ftanh(ep[k] + hL[k]);
                }
#pragma unroll
                for (int off = 32; off; off >>= 1) sc += __shfl_xor(sc, off);
                if (kq == 0) cohStoreU64(dst + l, packF2(sc, tagi));
            }
            __syncthreads();
        }
    } else if (bx < 176) {
        // ================= WT =================
        const int id = bx - 112;
        const int b = id >> 3, cq = id & 7;
        const int c = tid & 63, lg = tid >> 6;
        for (int t = 0; t < T_; ++t) {
            const float tagi = (float)(t + 1);
            if (tid < 256) {
                const u64* src = scEx + (t & 1) * 2048 + (b << 8);
                float2 f;
                for (;;) {
                    f = asF2(cohLoadU64(src + tid));
                    if (f.y == tagi) break;
                    __builtin_amdgcn_s_sleep(1);
                }
                mS[tid] = f.x;
            }
            __syncthreads();
            if (tid < 256) mS[256 + tid] = mS[tid];
            __syncthreads();
            for (int st = 128; st; st >>= 1) {
                if (tid < st) mS[256 + tid] = fmaxf(mS[256 + tid], mS[256 + tid + st]);
                __syncthreads();
            }
            float mx = mS[256];
            __syncthreads();
            if (tid < 256) { float ex = __expf(mS[tid] - mx); mS[tid] = ex; mS[256 + tid] = ex; }
            __syncthreads();
            for (int st = 128; st; st >>= 1) {
                if (tid < st) mS[256 + tid] += mS[256 + tid + st];
                __syncthreads();
            }
            float inv = 1.f / mS[256];
            // weighted cols (complete, no cross-WG reduce)
            float acc = 0.f;
            const float* eb = encOut + (((size_t)(b << 8)) << 9) + (cq << 6) + c;
#pragma unroll
            for (int m = 0; m < 32; ++m) {
                int l = lg + (m << 3);
                acc += mS[l] * eb[(size_t)l << 9];
            }
            mS[512 + lg * 64 + c] = acc;
            __syncthreads();
            if (tid < 64) {
                float wv = 0.f;
#pragma unroll
                for (int q = 0; q < 8; ++q) wv += mS[512 + q * 64 + tid];
                wv *= inv;
                cohStoreU64(wtEx + (t & 1) * 4096 + (b << 9) + (cq << 6) + tid, packF2(wv, tagi));
                mS[1024 + tid] = wv * wEff[512 + (cq << 6) + tid];
            }
            __syncthreads();
            if (tid == 0) {
                float pc = 0.f;
                for (int q = 0; q < 64; ++q) pc += mS[1024 + q];
                cpart[(b * T_ + t) * 48 + 32 + cq] = pc;
            }
            __syncthreads();
        }
    }
}

// c[b,t] = eDot4 + bEff + sum of 40 partials (32 GRU + 8 WT)
__global__ void k_csum(const float* __restrict__ cpart, const float* __restrict__ eDot4,
                       const float* __restrict__ bEff, float* __restrict__ cBuf) {
    int tid = threadIdx.x;
    if (tid < 192) {
        int b = tid / 24, t = tid % 24;
        float acc = eDot4[t * 8 + b] + bEff[0];
        const float* p = cpart + (b * T_ + t) * 48;
#pragma unroll
        for (int k = 0; k < 40; ++k) acc += p[k];
        cBuf[b * T_ + t] = acc;
    }
}

// out[b,t,l-part] = enc_dot[b,l] + c[b,t]
__global__ void k_final(const float* __restrict__ encDot, const float* __restrict__ c,
                        float* __restrict__ out) {
    int idx = blockIdx.x * 256 + threadIdx.x;  // grid 192 -> 49152
    const int half = B_ * T_ * S_;
    int w = idx < half ? idx : idx - half;
    int b = w / (T_ * S_);
    int r = w % (T_ * S_);
    int t = r / S_, sidx = r % S_;
    int l = (idx < half) ? sidx : (S_ + sidx);
    out[idx] = encDot[b * L_ + l] + c[b * T_ + t];
}

// ---------------------------------------------------------------------------
extern "C" void kernel_launch(void* const* d_in, const int* in_sizes, int n_in,
                              void* d_out, int out_size, void* d_ws, size_t ws_size,
                              hipStream_t stream) {
    const int* pre = (const int*)d_in[0];
    const int* post = (const int*)d_in[1];
    const int* trg = (const int*)d_in[2];
    const float* emb = (const float*)d_in[3];
    const float* WihPre = (const float*)d_in[4];
    const float* WhhPre = (const float*)d_in[5];
    const float* bihPre = (const float*)d_in[6];
    const float* bhhPre = (const float*)d_in[7];
    const float* WihPost = (const float*)d_in[8];
    const float* WhhPost = (const float*)d_in[9];
    const float* bihPost = (const float*)d_in[10];
    const float* bhhPost = (const float*)d_in[11];
    const float* fcEncW = (const float*)d_in[12];
    const float* fcEncB = (const float*)d_in[13];
    const float* attnW = (const float*)d_in[14];
    const float* attnB = (const float*)d_in[15];
    const float* attnV = (const float*)d_in[16];
    const float* WihDec = (const float*)d_in[17];
    const float* WhhDec = (const float*)d_in[18];
    const float* bihDec = (const float*)d_in[19];
    const float* bhhDec = (const float*)d_in[20];
    const float* fcHidW = (const float*)d_in[21];
    const float* fcHidB = (const float*)d_in[22];
    const float* fcOutW = (const float*)d_in[23];
    const float* fcOutB = (const float*)d_in[24];
    float* outp = (float*)d_out;

    float* base = (float*)d_ws;
    size_t off = 0;
    auto alloc = [&](size_t n) {
        float* p = base + off;
        off += (n + 63) & ~(size_t)63;
        return p;
    };
    float* giPre = alloc(1024 * 1536);
    float* giPost = alloc(1024 * 1536);
    float* giE = alloc(192 * 1536);
    float* encOut = alloc(8 * 256 * 512);
    float* encProj = alloc(8 * 256 * 512);
    float* wEff = alloc(2048);
    float* bEff = alloc(64);
    float* encDot = alloc(2048);
    float* eDot4 = alloc(256);
    float* hBuf = alloc(4096);
    float* cBuf = alloc(256);
    float* encExF = alloc(32768);             // 2 x 16 x 512 u64  (encoder h)
    float* hExF = alloc(16384);               // 2 x 4096 u64
    float* hpExF = alloc(16384);              // 2 x 4096 u64
    float* scExF = alloc(8192);               // 2 x 2048 u64
    float* wtExF = alloc(16384);              // 2 x 4096 u64
    float* cpart = alloc(8 * 24 * 48);
    int* idxPre = (int*)alloc(1024);
    int* idxPost = (int*)alloc(1024);
    int* idxTok = (int*)alloc(256);

    k_init<<<8, 256, 0, stream>>>(pre, post, trg, idxPre, idxPost, idxTok, wEff);
    // encEx + hEx + hpEx + scEx + wtEx are contiguous: one clear (45056 u64).
    k_clear<<<512, 256, 0, stream>>>((u64*)encExF, 45056);
    k_weff<<<129, 256, 0, stream>>>(fcHidW, fcHidB, fcOutW, fcOutB, wEff, bEff);
    k_gemm<<<dim3(16, 24), 256, 0, stream>>>(emb, idxPre, 512, WihPre, 512, bihPre, giPre, 1536, 512);
    k_gemm<<<dim3(16, 24), 256, 0, stream>>>(emb, idxPost, 512, WihPost, 512, bihPost, giPost, 1536, 512);
    k_gemm<<<dim3(3, 24), 256, 0, stream>>>(emb, idxTok, 512, WihDec, 1024, bihDec, giE, 1536, 512);
    k_encoder<<<256, 512, 0, stream>>>(giPre, giPost, WhhPre, WhhPost, bhhPre, bhhPost,
                                       encOut, (u64*)encExF);
    k_gemm<<<dim3(32, 8), 256, 0, stream>>>(encOut, nullptr, 512, attnW + 512, 1024, attnB, encProj, 512, 512);
    k_fcenc<<<16, 256, 0, stream>>>(encOut, fcEncW, fcEncB, hBuf);
    k_encdot<<<32, 256, 0, stream>>>(encOut, wEff, encDot);
    k_edot4<<<192, 64, 0, stream>>>(emb, idxTok, wEff, eDot4);
    k_decoder<<<176, 512, 0, stream>>>(encOut, encProj, attnW, attnV, WihDec, WhhDec, bhhDec,
                                       giE, wEff, hBuf, (u64*)hExF, (u64*)hpExF,
                                       (u64*)scExF, (u64*)wtExF, cpart);
    k_csum<<<1, 256, 0, stream>>>(cpart, eDot4, bEff, cBuf);
    k_final<<<192, 256, 0, stream>>>(encDot, cBuf, outp);
}

// Round 6
// 902.196 us; speedup vs baseline: 4.4697x; 1.1339x over previous
//
#include <hip/hip_runtime.h>
#include <cstdint>

#define B_ 8
#define S_ 128
#define T_ 24
#define E_ 512
#define H_ 512
#define H3_ 1536
#define L_ 256
#define D_ 2048

typedef unsigned long long u64;

__device__ __forceinline__ float fsig(float x) { return 1.0f / (1.0f + __expf(-x)); }
__device__ __forceinline__ float ftanh(float x) { return 1.0f - 2.0f / (1.0f + __expf(2.0f * x)); }
__device__ __forceinline__ float dot4(float4 a, float4 b) {
    return a.x * b.x + a.y * b.y + a.z * b.z + a.w * b.w;
}

// Coherent (LLC-level) 8B atoms: relaxed agent-scope atomics compile to
// global_load/store sc0 sc1 — bypass non-coherent L1/L2, no cache flushes.
__device__ __forceinline__ u64 cohLoadU64(const u64* p) {
    return __hip_atomic_load((u64*)p, __ATOMIC_RELAXED, __HIP_MEMORY_SCOPE_AGENT);
}
__device__ __forceinline__ void cohStoreU64(u64* p, u64 v) {
    __hip_atomic_store(p, v, __ATOMIC_RELAXED, __HIP_MEMORY_SCOPE_AGENT);
}
__device__ __forceinline__ float2 asF2(u64 v) { union { u64 u; float2 f; } x; x.u = v; return x.f; }
__device__ __forceinline__ u64 packF2(float v, float tag) { union { float2 f; u64 u; } x; x.f = make_float2(v, tag); return x.u; }

// ---------------------------------------------------------------------------
// boot: clear tagged exchange buffers + index prep (one launch)
// ---------------------------------------------------------------------------
__global__ void k_boot(const int* __restrict__ pre, const int* __restrict__ post,
                       const int* __restrict__ trg,
                       int* __restrict__ idxPre, int* __restrict__ idxPost,
                       int* __restrict__ idxTok, float* __restrict__ wEff,
                       u64* __restrict__ clr, int n) {
    int gtid = blockIdx.x * 256 + threadIdx.x;  // 512 x 256
    for (int i = gtid; i < n; i += gridDim.x * 256) clr[i] = 0ull;
    if (gtid < 1024) {
        int s = gtid >> 3, b = gtid & 7;
        idxPre[gtid]  = pre[b * S_ + s];
        idxPost[gtid] = post[b * S_ + s];
    }
    if (gtid < T_ * B_) {
        int t = gtid >> 3, b = gtid & 7;
        idxTok[gtid] = (t == 0) ? pre[b * S_ + (S_ - 1)] : trg[b * T_ + (t - 1)];
    }
    if (gtid < 2048) wEff[gtid] = 0.f;
}

// ---------------------------------------------------------------------------
// Tiled f32 GEMM body (device fn): C[m][n] = sum_k A[m][k]*B[n][k] + bias[n]
// ---------------------------------------------------------------------------
__device__ void gemm_body(
    const float* __restrict__ A, const int* __restrict__ Aidx, int lda,
    const float* __restrict__ Bm, int ldb,
    const float* __restrict__ bias, float* __restrict__ C,
    int N, int K, int gbx, int gby) {
    __shared__ float As[16][68];
    __shared__ float Bs[16][68];
    const int m0 = gbx * 64, n0 = gby * 64;
    const int tid = threadIdx.x;
    const int tm = tid >> 2;
    const int tk = (tid & 3) << 2;
    const int tx = tid & 15, ty = tid >> 4;
    const int am = m0 + tm;
    const float* Arow = A + (size_t)(Aidx ? Aidx[am] : am) * lda;
    const float* Brow = Bm + (size_t)(n0 + tm) * ldb;
    float acc[4][4] = {};
    for (int k0 = 0; k0 < K; k0 += 16) {
        float4 av = *(const float4*)(Arow + k0 + tk);
        float4 bv = *(const float4*)(Brow + k0 + tk);
        __syncthreads();
        As[tk][tm] = av.x; As[tk + 1][tm] = av.y; As[tk + 2][tm] = av.z; As[tk + 3][tm] = av.w;
        Bs[tk][tm] = bv.x; Bs[tk + 1][tm] = bv.y; Bs[tk + 2][tm] = bv.z; Bs[tk + 3][tm] = bv.w;
        __syncthreads();
#pragma unroll
        for (int k = 0; k < 16; ++k) {
            float4 a4 = *(const float4*)(&As[k][ty << 2]);
            float4 b4 = *(const float4*)(&Bs[k][tx << 2]);
            float ar[4] = {a4.x, a4.y, a4.z, a4.w};
            float br[4] = {b4.x, b4.y, b4.z, b4.w};
#pragma unroll
            for (int i = 0; i < 4; ++i)
#pragma unroll
                for (int j = 0; j < 4; ++j) acc[i][j] += ar[i] * br[j];
        }
    }
    float4 bb = bias ? *(const float4*)(bias + n0 + (tx << 2)) : make_float4(0.f, 0.f, 0.f, 0.f);
#pragma unroll
    for (int i = 0; i < 4; ++i) {
        int m = m0 + (ty << 2) + i;
        float4 o;
        o.x = acc[i][0] + bb.x; o.y = acc[i][1] + bb.y;
        o.z = acc[i][2] + bb.z; o.w = acc[i][3] + bb.w;
        *(float4*)(C + (size_t)m * N + n0 + (tx << 2)) = o;
    }
}

// ---------------------------------------------------------------------------
// k_mid: role-split concurrent launch of the post-encoder prep:
//   [0,72)    giE   = emb[tok] @ WihDec[:, :512].T + bihDec   (3 x 24 tiles)
//   [72,328)  encProj = encOut @ W_enc.T + attnB              (32 x 8 tiles)
//   [328,457) wEff = fc_out_W @ fc_hid_W ; bEff
//   [457,473) hBuf = tanh([pre_h, post_h] @ fc_enc_W.T + b)
// ---------------------------------------------------------------------------
__global__ __launch_bounds__(256) void k_mid(
    const float* __restrict__ emb, const int* __restrict__ idxTok,
    const float* __restrict__ WihDec, const float* __restrict__ bihDec, float* __restrict__ giE,
    const float* __restrict__ encOut, const float* __restrict__ attnW,
    const float* __restrict__ attnB, float* __restrict__ encProj,
    const float* __restrict__ fcHidW, const float* __restrict__ fcHidB,
    const float* __restrict__ fcOutW, const float* __restrict__ fcOutB,
    float* __restrict__ wEff, float* __restrict__ bEff,
    const float* __restrict__ fcEncW, const float* __restrict__ fcEncB,
    float* __restrict__ hBuf) {
    const int bx = blockIdx.x;
    const int tid = threadIdx.x;
    if (bx < 72) {
        gemm_body(emb, idxTok, 512, WihDec, 1024, bihDec, giE, 1536, 512, bx % 3, bx / 3);
    } else if (bx < 328) {
        int r = bx - 72;
        gemm_body(encOut, nullptr, 512, attnW + 512, 1024, attnB, encProj, 512, 512, r & 31, r >> 5);
    } else if (bx < 457) {
        __shared__ float red[256];
        int wb = bx - 328;
        if (wb < 128) {
            int cblk = wb & 7, q = wb >> 3;
            int col = cblk * 256 + tid;
            int j0 = q * 128;
            float acc = 0.f;
            for (int j = j0; j < j0 + 128; ++j) acc += fcOutW[j] * fcHidW[(size_t)j * D_ + col];
            atomicAdd(wEff + col, acc);
        } else {
            float p = 0.f;
            for (int j = tid; j < D_; j += 256) p += fcOutW[j] * fcHidB[j];
            red[tid] = p;
            __syncthreads();
            for (int s = 128; s > 0; s >>= 1) {
                if (tid < s) red[tid] += red[tid + s];
                __syncthreads();
            }
            if (tid == 0) bEff[0] = red[0] + fcOutB[0];
        }
    } else {
        int o = (bx - 457) * 256 + tid;  // 4096
        int b = o >> 9, j = o & 511;
        const float4* w4 = (const float4*)(fcEncW + (size_t)j * 1024);
        const float4* pre4 = (const float4*)(encOut + (((size_t)(b << 8) + 127) << 9));
        const float4* post4 = (const float4*)(encOut + (((size_t)(b << 8) + 255) << 9));
        float acc = fcEncB[j];
        for (int k = 0; k < 128; ++k) acc += dot4(w4[k], pre4[k]);
        for (int k = 0; k < 128; ++k) acc += dot4(w4[128 + k], post4[k]);
        hBuf[o] = ftanh(acc);
    }
}

// ---------------------------------------------------------------------------
// Encoder scan, col-split + h-broadcast tagged sync, gi INLINED:
// thread (c,l) holds Whh AND Wih rows {j,512+j,1024+j} seg [32l,32l+32) in
// VGPRs (192 floats). Per step: prefetch emb[tok] row (2KB coalesced) -> poll
// ONE tagged h slot -> LDS (pad-36) -> 192 reg FMA (gh+gi fused) -> width-16
// shfl reduce -> lane0 gates -> publish 32 tagged h2.
// The two 1024x1536x512 gi GEMMs (~130us serial) are deleted.
// ---------------------------------------------------------------------------
__global__ __launch_bounds__(512, 2) void k_encoder(
    const float* __restrict__ emb, const int* __restrict__ idxPre, const int* __restrict__ idxPost,
    const float* __restrict__ WihPre, const float* __restrict__ WihPost,
    const float* __restrict__ bihPre, const float* __restrict__ bihPost,
    const float* __restrict__ WhhPre, const float* __restrict__ WhhPost,
    const float* __restrict__ bhhPre, const float* __restrict__ bhhPost,
    float* __restrict__ encOut, u64* __restrict__ encEx) {
    const int bx = blockIdx.x;        // 0..255
    const int chain = bx >> 4;        // gr = chain>>3, b = chain&7
    const int p = bx & 15;
    const int gr = chain >> 3, b = chain & 7;
    const int kb = p << 5;
    const int tid = threadIdx.x;
    const int c = tid >> 4, l = tid & 15;
    const int j = kb + c;
    const float* Wih = gr ? WihPost : WihPre;
    const float* bih = gr ? bihPost : bihPre;
    const float* Whh = gr ? WhhPost : WhhPre;
    const float* bhh = gr ? bhhPost : bhhPre;
    const int* idx = gr ? idxPost : idxPre;
    u64* ex0 = encEx + chain * 512;

    __shared__ float hS[576];   // [16 segs][36] padded
    __shared__ float eS[576];

    float wr[32], wz[32], wn[32], ur[32], uz[32], un[32];
    {
        const float* r0 = Whh + (size_t)j * 512 + l * 32;
        const float* r1 = r0 + 512 * 512;
        const float* r2 = r1 + 512 * 512;
        const float* u0 = Wih + (size_t)j * 512 + l * 32;
        const float* u1 = u0 + 512 * 512;
        const float* u2 = u1 + 512 * 512;
#pragma unroll
        for (int m = 0; m < 32; ++m) {
            wr[m] = r0[m]; wz[m] = r1[m]; wn[m] = r2[m];
            ur[m] = u0[m]; uz[m] = u1[m]; un[m] = u2[m];
        }
    }
    const float b0 = bih[j] + bhh[j];
    const float b1 = bih[512 + j] + bhh[512 + j];
    const float bi2 = bih[1024 + j];
    const float bh2 = bhh[1024 + j];

    for (int t = 0; t < S_; ++t) {
        int tok = idx[t * 8 + b];
        float ev = emb[(size_t)tok * 512 + tid];   // issued early, hides under poll
        if (t == 0) {
            hS[(tid >> 5) * 36 + (tid & 31)] = 0.f;
        } else {
            const float tag = (float)t;
            const u64* src = ex0 + (t & 1) * 8192;
            float v;
            for (;;) {
                float2 f = asF2(cohLoadU64(src + tid));
                if (f.y == tag) { v = f.x; break; }
                __builtin_amdgcn_s_sleep(1);
            }
            hS[(tid >> 5) * 36 + (tid & 31)] = v;
        }
        eS[(tid >> 5) * 36 + (tid & 31)] = ev;
        __syncthreads();
        const float* hseg = hS + l * 36;
        const float* eseg = eS + l * 36;
        float a0 = 0.f, a1 = 0.f, a2h = 0.f, a2i = 0.f;
#pragma unroll
        for (int m = 0; m < 32; ++m) {
            float hv = hseg[m], evv = eseg[m];
            a0 += wr[m] * hv + ur[m] * evv;
            a1 += wz[m] * hv + uz[m] * evv;
            a2h += wn[m] * hv;
            a2i += un[m] * evv;
        }
#pragma unroll
        for (int off = 8; off; off >>= 1) {
            a0 += __shfl_xor(a0, off, 16);
            a1 += __shfl_xor(a1, off, 16);
            a2h += __shfl_xor(a2h, off, 16);
            a2i += __shfl_xor(a2i, off, 16);
        }
        if (l == 0) {
            float r = fsig(a0 + b0);
            float z = fsig(a1 + b1);
            float n = ftanh(a2i + bi2 + r * (a2h + bh2));
            float h2 = (1.f - z) * n + z * hS[p * 36 + c];
            cohStoreU64(ex0 + ((t + 1) & 1) * 8192 + j, packF2(h2, (float)(t + 1)));
            encOut[(((size_t)(b << 8) + (gr << 7) + t) << 9) + j] = h2;
        }
        __syncthreads();
    }
}

// ---------------------------------------------------------------------------
// Decoder: 3-hop dataflow. HP role DELETED: GRU WGs publish hp-PARTIALS
// (attnW_hid col-slice x own 16 h-cols) right after the gates; SC sums 32
// partials in one batched tagged round trip. gh uses the proven round-4 hEx
// h-exchange (published 1 hop after gates, consumed 3 hops later: off-path).
//   roles: [0,32) GRU | [32,96) SC (b,lq) | [96,160) WT (b,cq)
//          [160,164) encdot | [164,188) edot4   (shadow work)
// Critical chain/step: gates -> hpP -> SC -> sc -> WT -> wt -> gates.
// All static LDS <= 39KB (round-5's 70KB SC/WT staging removed: the staged
// slices are L2-resident, ~0.1us/step to re-read).
// ---------------------------------------------------------------------------
__global__ __launch_bounds__(512, 2) void k_decoder(
    const float* __restrict__ encOut, const float* __restrict__ encProj,
    const float* __restrict__ attnW, const float* __restrict__ attnV,
    const float* __restrict__ WihDec, const float* __restrict__ WhhDec,
    const float* __restrict__ bhhDec, const float* __restrict__ giE,
    const float* __restrict__ wEff, const float* __restrict__ hBuf,
    const float* __restrict__ emb, const int* __restrict__ idxTok,
    u64* __restrict__ hEx, u64* __restrict__ hpP,
    u64* __restrict__ scEx, u64* __restrict__ wtEx,
    float* __restrict__ cpart, float* __restrict__ encDot, float* __restrict__ eDot4) {
    const int tid = threadIdx.x;
    const int bx = blockIdx.x;
    __shared__ float shm[9664];

    if (bx < 32) {
        // ================= GRU =================
        const int g = bx;
        const int s = tid >> 5, kq = tid & 31;
        const int j = (g << 4) + s;
        float wr[16], wz[16], wn[16], vr[16], vz[16], vn[16], ap[16];
#pragma unroll
        for (int m = 0; m < 16; ++m) {
            int k = kq + 32 * m;
            wr[m] = WhhDec[(size_t)j * 512 + k];
            wz[m] = WhhDec[(size_t)(512 + j) * 512 + k];
            wn[m] = WhhDec[(size_t)(1024 + j) * 512 + k];
            vr[m] = WihDec[(size_t)j * 1024 + 512 + k];
            vz[m] = WihDec[(size_t)(512 + j) * 1024 + 512 + k];
            vn[m] = WihDec[(size_t)(1024 + j) * 1024 + 512 + k];
            ap[m] = attnW[(size_t)tid * 1024 + (g << 4) + m];  // W_hid row=tid, col=16g+m
        }
        float* hL = shm;          // 4096: full h(t)
        float* xL = shm + 4096;   // 4096: weighted
        float* mS = shm + 8192;   // 1456 scratch
        // mS: [0,384) gh [q48][b8] | [384,768) giw | [768,1152) giE |
        //     [1152,1280) h2 slice [ss][b] | [1280,1328) bhh | [1328,1456) logit
        if (tid < 128) { int ss = tid >> 3, bb = tid & 7; mS[1152 + tid] = hBuf[(bb << 9) + (g << 4) + ss]; }
        if (tid < 48) mS[1280 + tid] = bhhDec[(tid >> 4) * 512 + (g << 4) + (tid & 15)];
        __syncthreads();
        // publish hpP(h(0)) tag 1, parity 0
        {
            u64* hdst = hpP + (size_t)g * 4096;
#pragma unroll
            for (int bb = 0; bb < 8; ++bb) {
                float acch = 0.f;
#pragma unroll
                for (int m = 0; m < 16; ++m) acch += ap[m] * mS[1152 + m * 8 + bb];
                cohStoreU64(hdst + bb * 512 + tid, packF2(acch, 1.0f));
            }
        }
        for (int t = 0; t < T_; ++t) {
            const int par = t & 1;
            const float tagi = (float)(t + 1);
            // ---- stage h(t): t==0 from hBuf, else batched poll on hEx ----
            if (t == 0) {
#pragma unroll
                for (int i = 0; i < 8; ++i) hL[tid + 512 * i] = hBuf[tid + 512 * i];
            } else {
                const float tagh = (float)t;
                const u64* src = hEx + par * 4096;
                float v[8];
                for (;;) {
                    u64 rr[8]; bool ok = true;
#pragma unroll
                    for (int i = 0; i < 8; ++i) rr[i] = cohLoadU64(src + tid + 512 * i);
#pragma unroll
                    for (int i = 0; i < 8; ++i) { float2 f = asF2(rr[i]); v[i] = f.x; ok &= (f.y == tagh); }
                    if (ok) break;
                    __builtin_amdgcn_s_sleep(1);
                }
#pragma unroll
                for (int i = 0; i < 8; ++i) hL[tid + 512 * i] = v[i];
            }
            __syncthreads();
            // ---- gh = Whh.h (own 16 cols, all batches) ----
            for (int bb = 0; bb < 8; ++bb) {
                const float* hb = hL + (bb << 9);
                float ar = 0.f, az = 0.f, an = 0.f;
#pragma unroll
                for (int m = 0; m < 16; ++m) {
                    float hv = hb[kq + 32 * m];
                    ar += wr[m] * hv; az += wz[m] * hv; an += wn[m] * hv;
                }
#pragma unroll
                for (int off = 16; off; off >>= 1) {
                    ar += __shfl_xor(ar, off); az += __shfl_xor(az, off); an += __shfl_xor(an, off);
                }
                if (kq == 0) {
                    mS[s * 8 + bb]       = ar;
                    mS[128 + s * 8 + bb] = az;
                    mS[256 + s * 8 + bb] = an;
                }
            }
            // ---- giE prefetch (overlaps wt poll) ----
            if (tid < 384) {
                int bb = tid / 48, idx2 = tid % 48, g3 = idx2 >> 4, ss = idx2 & 15;
                mS[768 + g3 * 128 + ss * 8 + bb] =
                    giE[((size_t)(t << 3) + bb) * H3_ + g3 * 512 + (g << 4) + ss];
            }
            // ---- poll weighted (critical, batched) ----
            {
                const u64* src = wtEx + par * 4096;
                float v[8];
                for (;;) {
                    u64 rr[8]; bool ok = true;
#pragma unroll
                    for (int i = 0; i < 8; ++i) rr[i] = cohLoadU64(src + tid + 512 * i);
#pragma unroll
                    for (int i = 0; i < 8; ++i) { float2 f = asF2(rr[i]); v[i] = f.x; ok &= (f.y == tagi); }
                    if (ok) break;
                    __builtin_amdgcn_s_sleep(1);
                }
#pragma unroll
                for (int i = 0; i < 8; ++i) xL[tid + 512 * i] = v[i];
            }
            __syncthreads();
            // ---- giw = Wih_half . weighted ----
            for (int bb = 0; bb < 8; ++bb) {
                const float* wb = xL + (bb << 9);
                float ar = 0.f, az = 0.f, an = 0.f;
#pragma unroll
                for (int m = 0; m < 16; ++m) {
                    float wv = wb[kq + 32 * m];
                    ar += vr[m] * wv; az += vz[m] * wv; an += vn[m] * wv;
                }
#pragma unroll
                for (int off = 16; off; off >>= 1) {
                    ar += __shfl_xor(ar, off); az += __shfl_xor(az, off); an += __shfl_xor(an, off);
                }
                if (kq == 0) {
                    mS[384 + s * 8 + bb] = ar;
                    mS[512 + s * 8 + bb] = az;
                    mS[640 + s * 8 + bb] = an;
                }
            }
            __syncthreads();
            // ---- gates + h publish + logit partial ----
            if (tid < 128) {
                int ss = tid >> 3, bb = tid & 7;
                int jj = (g << 4) + ss;
                int o = ss * 8 + bb;
                float ghr = mS[o]       + mS[1280 + ss];
                float ghz = mS[128 + o] + mS[1296 + ss];
                float ghn = mS[256 + o] + mS[1312 + ss];
                float gir = mS[384 + o] + mS[768 + o];
                float giz = mS[512 + o] + mS[896 + o];
                float gin = mS[640 + o] + mS[1024 + o];
                float r = fsig(gir + ghr), z = fsig(giz + ghz);
                float n = ftanh(gin + r * ghn);
                float h2 = (1.f - z) * n + z * hL[(bb << 9) + jj];
                cohStoreU64(hEx + ((t + 1) & 1) * 4096 + (bb << 9) + jj, packF2(h2, (float)(t + 1)));
                mS[1152 + o] = h2;
                mS[1328 + o] = h2 * wEff[1024 + jj];
            }
            __syncthreads();
            if (tid < 8) {
                float pc = 0.f;
#pragma unroll
                for (int q = 0; q < 16; ++q) pc += mS[1328 + q * 8 + tid];
                cpart[(tid * T_ + t) * 48 + g] = pc;
            }
            // ---- publish hpP(h(t+1)) tag t+2, parity (t+1)&1 ----
            if (t < T_ - 1) {
                const float tg = (float)(t + 2);
                u64* hdst = hpP + (size_t)((t + 1) & 1) * 131072 + (size_t)g * 4096;
#pragma unroll
                for (int bb = 0; bb < 8; ++bb) {
                    float acch = 0.f;
#pragma unroll
                    for (int m = 0; m < 16; ++m) acch += ap[m] * mS[1152 + m * 8 + bb];
                    cohStoreU64(hdst + bb * 512 + tid, packF2(acch, tg));
                }
            }
            __syncthreads();
        }
    } else if (bx < 96) {
        // ================= SC =================
        const int id = bx - 32;
        const int b = id >> 3, lq = id & 7;
        float* hpS = shm;          // 512
        float* vS  = shm + 512;    // 512
        vS[tid] = attnV[tid];
        __syncthreads();
        const int kq = tid & 63, lg = tid >> 6;
        for (int t = 0; t < T_; ++t) {
            const int par = t & 1;
            const float tagi = (float)(t + 1);
            // gather 32 hp-partials (batched: one LLC round trip)
            {
                const u64* src = hpP + (size_t)par * 131072 + (size_t)b * 512 + tid;
                float sum;
                for (;;) {
                    bool ok = true; float s2 = 0.f;
                    u64 ra[16];
#pragma unroll
                    for (int pp = 0; pp < 16; ++pp) ra[pp] = cohLoadU64(src + (size_t)pp * 4096);
#pragma unroll
                    for (int pp = 0; pp < 16; ++pp) { float2 f = asF2(ra[pp]); s2 += f.x; ok &= (f.y == tagi); }
#pragma unroll
                    for (int pp = 0; pp < 16; ++pp) ra[pp] = cohLoadU64(src + (size_t)(16 + pp) * 4096);
#pragma unroll
                    for (int pp = 0; pp < 16; ++pp) { float2 f = asF2(ra[pp]); s2 += f.x; ok &= (f.y == tagi); }
                    if (ok) { sum = s2; break; }
                    __builtin_amdgcn_s_sleep(2);
                }
                hpS[tid] = sum;
            }
            __syncthreads();
            u64* dst = scEx + par * 2048 + (b << 8);
#pragma unroll
            for (int i = 0; i < 4; ++i) {
                int ll = lg + (i << 3);
                const float* ep = encProj + (((size_t)(b << 8) + (lq << 5) + ll) << 9);
                float sc = 0.f;
#pragma unroll
                for (int m = 0; m < 8; ++m) {
                    int k = kq + (m << 6);
                    sc += vS[k] * ftanh(ep[k] + hpS[k]);
                }
#pragma unroll
                for (int off = 32; off; off >>= 1) sc += __shfl_xor(sc, off);
                if (kq == 0) cohStoreU64(dst + (lq << 5) + ll, packF2(sc, tagi));
            }
            __syncthreads();
        }
    } else if (bx < 160) {
        // ================= WT =================
        const int id = bx - 96;
        const int b = id >> 3, cq = id & 7;
        const int c = tid & 63, lg = tid >> 6;
        float* aS = shm;          // 256
        float* rS = shm + 256;    // 16
        float* wS = shm + 288;    // 512
        float* lp = shm + 800;    // 64
        for (int t = 0; t < T_; ++t) {
            const int par = t & 1;
            const float tagi = (float)(t + 1);
            float sc = 0.f;
            if (tid < 256) {
                const u64* src = scEx + par * 2048 + (b << 8) + tid;
                for (;;) {
                    float2 f = asF2(cohLoadU64(src));
                    if (f.y == tagi) { sc = f.x; break; }
                    __builtin_amdgcn_s_sleep(1);
                }
            }
            // shfl softmax (waves 0-3 hold the 256 scores)
            float m = (tid < 256) ? sc : -1e30f;
#pragma unroll
            for (int off = 32; off; off >>= 1) m = fmaxf(m, __shfl_xor(m, off));
            if ((tid & 63) == 0) rS[tid >> 6] = m;
            __syncthreads();
            float mx = fmaxf(fmaxf(rS[0], rS[1]), fmaxf(rS[2], rS[3]));
            float e = (tid < 256) ? __expf(sc - mx) : 0.f;
            float ssum = e;
#pragma unroll
            for (int off = 32; off; off >>= 1) ssum += __shfl_xor(ssum, off);
            if ((tid & 63) == 0) rS[8 + (tid >> 6)] = ssum;
            if (tid < 256) aS[tid] = e;
            __syncthreads();
            float inv = 1.f / (rS[8] + rS[9] + rS[10] + rS[11]);
            // weighted cols (complete, no cross-WG reduce); encOut slice L2-hot
            float acc = 0.f;
#pragma unroll
            for (int mm = 0; mm < 32; ++mm) {
                int l = lg + (mm << 3);
                acc += aS[l] * encOut[(((size_t)(b << 8) + l) << 9) + (cq << 6) + c];
            }
            wS[lg * 64 + c] = acc;
            __syncthreads();
            if (tid < 64) {
                float wv = 0.f;
#pragma unroll
                for (int q = 0; q < 8; ++q) wv += wS[q * 64 + tid];
                wv *= inv;
                cohStoreU64(wtEx + par * 4096 + (b << 9) + (cq << 6) + tid, packF2(wv, tagi));
                lp[tid] = wv * wEff[512 + (cq << 6) + tid];
            }
            __syncthreads();
            if (tid == 0) {
                float pc = 0.f;
                for (int q = 0; q < 64; ++q) pc += lp[q];
                cpart[(b * T_ + t) * 48 + 32 + cq] = pc;
            }
            __syncthreads();
        }
    } else if (bx < 164) {
        // ================= encdot (shadow) =================
        int wid = tid >> 6, lane = tid & 63;
        int gw = (bx - 160) * 8 + wid;  // 32 waves
        for (int o = gw; o < 2048; o += 32) {
            const float* row = encOut + ((size_t)o << 9);
            float s = 0.f;
            for (int k = lane; k < 512; k += 64) s += row[k] * wEff[k];
            for (int off = 32; off; off >>= 1) s += __shfl_down(s, off);
            if (lane == 0) encDot[o] = s;
        }
    } else {
        // ================= edot4 (shadow) =================
        int wg = bx - 164;              // 24 WGs x 8 rows
        int o = wg * 8 + (tid >> 6);
        int lane = tid & 63;
        const float* row = emb + (size_t)idxTok[o] * E_;
        const float* w = wEff + 1536;
        float s = 0.f;
        for (int k = lane; k < 512; k += 64) s += row[k] * w[k];
        for (int off = 32; off; off >>= 1) s += __shfl_down(s, off);
        if (lane == 0) eDot4[o] = s;
    }
}

// c[b,t] = eDot4 + bEff + sum of 40 partials (32 GRU + 8 WT)
__global__ void k_csum(const float* __restrict__ cpart, const float* __restrict__ eDot4,
                       const float* __restrict__ bEff, float* __restrict__ cBuf) {
    int tid = threadIdx.x;
    if (tid < 192) {
        int b = tid / 24, t = tid % 24;
        float acc = eDot4[t * 8 + b] + bEff[0];
        const float* p = cpart + (b * T_ + t) * 48;
#pragma unroll
        for (int k = 0; k < 40; ++k) acc += p[k];
        cBuf[b * T_ + t] = acc;
    }
}

// out[b,t,l-part] = enc_dot[b,l] + c[b,t]
__global__ void k_final(const float* __restrict__ encDot, const float* __restrict__ c,
                        float* __restrict__ out) {
    int idx = blockIdx.x * 256 + threadIdx.x;  // grid 192 -> 49152
    const int half = B_ * T_ * S_;
    int w = idx < half ? idx : idx - half;
    int b = w / (T_ * S_);
    int r = w % (T_ * S_);
    int t = r / S_, sidx = r % S_;
    int l = (idx < half) ? sidx : (S_ + sidx);
    out[idx] = encDot[b * L_ + l] + c[b * T_ + t];
}

// ---------------------------------------------------------------------------
extern "C" void kernel_launch(void* const* d_in, const int* in_sizes, int n_in,
                              void* d_out, int out_size, void* d_ws, size_t ws_size,
                              hipStream_t stream) {
    const int* pre = (const int*)d_in[0];
    const int* post = (const int*)d_in[1];
    const int* trg = (const int*)d_in[2];
    const float* emb = (const float*)d_in[3];
    const float* WihPre = (const float*)d_in[4];
    const float* WhhPre = (const float*)d_in[5];
    const float* bihPre = (const float*)d_in[6];
    const float* bhhPre = (const float*)d_in[7];
    const float* WihPost = (const float*)d_in[8];
    const float* WhhPost = (const float*)d_in[9];
    const float* bihPost = (const float*)d_in[10];
    const float* bhhPost = (const float*)d_in[11];
    const float* fcEncW = (const float*)d_in[12];
    const float* fcEncB = (const float*)d_in[13];
    const float* attnW = (const float*)d_in[14];
    const float* attnB = (const float*)d_in[15];
    const float* attnV = (const float*)d_in[16];
    const float* WihDec = (const float*)d_in[17];
    const float* WhhDec = (const float*)d_in[18];
    const float* bihDec = (const float*)d_in[19];
    const float* bhhDec = (const float*)d_in[20];
    const float* fcHidW = (const float*)d_in[21];
    const float* fcHidB = (const float*)d_in[22];
    const float* fcOutW = (const float*)d_in[23];
    const float* fcOutB = (const float*)d_in[24];
    float* outp = (float*)d_out;

    float* base = (float*)d_ws;
    size_t off = 0;
    auto alloc = [&](size_t n) {
        float* p = base + off;
        off += (n + 63) & ~(size_t)63;
        return p;
    };
    float* giE = alloc(192 * 1536);
    float* encOut = alloc(8 * 256 * 512);
    float* encProj = alloc(8 * 256 * 512);
    float* wEff = alloc(2048);
    float* bEff = alloc(64);
    float* encDot = alloc(2048);
    float* eDot4 = alloc(256);
    float* hBuf = alloc(4096);
    float* cBuf = alloc(256);
    // contiguous tagged-exchange region (cleared each launch):
    float* encExF = alloc(32768);     // 2 x 16 x 512 u64   encoder h
    float* hExF  = alloc(16384);      // 2 x 4096 u64       decoder h
    float* hpPF  = alloc(524288);     // 2 x 32 x 4096 u64  hp partials
    float* scExF = alloc(8192);       // 2 x 2048 u64
    float* wtExF = alloc(16384);      // 2 x 4096 u64
    float* cpart = alloc(8 * 24 * 48);
    int* idxPre = (int*)alloc(1024);
    int* idxPost = (int*)alloc(1024);
    int* idxTok = (int*)alloc(256);

    const int clearN = (32768 + 16384 + 524288 + 8192 + 16384) / 2;  // u64 slots
    k_boot<<<512, 256, 0, stream>>>(pre, post, trg, idxPre, idxPost, idxTok, wEff,
                                    (u64*)encExF, clearN);
    k_encoder<<<256, 512, 0, stream>>>(emb, idxPre, idxPost, WihPre, WihPost,
                                       bihPre, bihPost, WhhPre, WhhPost,
                                       bhhPre, bhhPost, encOut, (u64*)encExF);
    k_mid<<<473, 256, 0, stream>>>(emb, idxTok, WihDec, bihDec, giE,
                                   encOut, attnW, attnB, encProj,
                                   fcHidW, fcHidB, fcOutW, fcOutB, wEff, bEff,
                                   fcEncW, fcEncB, hBuf);
    k_decoder<<<188, 512, 0, stream>>>(encOut, encProj, attnW, attnV,
                                       WihDec, WhhDec, bhhDec, giE, wEff, hBuf,
                                       emb, idxTok,
                                       (u64*)hExF, (u64*)hpPF, (u64*)scExF, (u64*)wtExF,
                                       cpart, encDot, eDot4);
    k_csum<<<1, 256, 0, stream>>>(cpart, eDot4, bEff, cBuf);
    k_final<<<192, 256, 0, stream>>>(encDot, cBuf, outp);
}